// Round 4
// baseline (253.654 us; speedup 1.0000x reference)
//
#include <hip/hip_runtime.h>
#include <math.h>

#define NB 4
#define SL 1024
#define EMB 1024
#define NH 16
#define HD 64
#define QB 64

typedef __attribute__((ext_vector_type(8))) short bf16x8;
typedef __attribute__((ext_vector_type(4))) float f32x4;
typedef __attribute__((ext_vector_type(4))) unsigned u32x4;

// round-half-up f32->bf16 pack (inputs finite)
static __device__ __forceinline__ unsigned pk2(float a, float b) {
    unsigned x = __float_as_uint(a) + 0x8000u;
    unsigned y = __float_as_uint(b) + 0x8000u;
    return (x >> 16) | (y & 0xFFFF0000u);
}
static __device__ __forceinline__ float exp2_fast(float x) {
    float r; asm("v_exp_f32 %0, %1" : "=v"(r) : "v"(x)); return r;
}
static __device__ __forceinline__ void gload_lds16(const void* g, void* l) {
    __builtin_amdgcn_global_load_lds(
        (const __attribute__((address_space(1))) unsigned int*)g,
        (__attribute__((address_space(3))) unsigned int*)l, 16, 0, 0);
}

#define MEMPIN() asm volatile("" ::: "memory")

// ---------------- Fused prep: W conv | K conv+split | V transpose | mask bitmask ----------------
__global__ __launch_bounds__(256) void prep(
    const float* __restrict__ W, unsigned short* __restrict__ Wb,
    const float* __restrict__ Kf, unsigned short* __restrict__ Kb,
    const float* __restrict__ V, unsigned short* __restrict__ Vt,
    const int* __restrict__ mask, unsigned long long* __restrict__ Mbt)
{
    __shared__ unsigned short sT[128 * 68];
    const int bid = blockIdx.x, tid = threadIdx.x;

    if (bid < 512) {
        int i = (bid * 256 + tid) * 8;
        float4 f0 = *(const float4*)&W[i];
        float4 f1 = *(const float4*)&W[i + 4];
        uint4 u = { pk2(f0.x,f0.y), pk2(f0.z,f0.w), pk2(f1.x,f1.y), pk2(f1.z,f1.w) };
        *(uint4*)&Wb[i] = u;
    } else if (bid < 2560) {
        int t = bid - 512;
        int b = t >> 9, h = (t >> 5) & 15, k0 = (t & 31) * 32;
        int r = tid >> 3, d = (tid & 7) * 8;
        const float* gp = &Kf[((size_t)(b * SL + k0 + r)) * EMB + h * HD + d];
        float4 f0 = *(const float4*)gp, f1 = *(const float4*)(gp + 4);
        uint4 u = { pk2(f0.x,f0.y), pk2(f0.z,f0.w), pk2(f1.x,f1.y), pk2(f1.z,f1.w) };
        *(uint4*)&Kb[((size_t)((b * NH + h) * SL + k0 + r)) * HD + d] = u;
    } else if (bid < 3072) {
        int t = bid - 2560;
        int bh = t >> 3, kb = t & 7;
        int b = bh >> 4, h = bh & 15;
        int k0 = kb * 128;
        #pragma unroll
        for (int i = 0; i < 4; ++i) {
            int lin = (i * 256 + tid) * 8;
            int r = lin >> 6, d = lin & 63;
            const float* gp = &V[((size_t)(b * SL + k0 + r)) * EMB + h * HD + d];
            float4 f0 = *(const float4*)gp, f1 = *(const float4*)(gp + 4);
            uint2 u0 = { pk2(f0.x,f0.y), pk2(f0.z,f0.w) };
            uint2 u1 = { pk2(f1.x,f1.y), pk2(f1.z,f1.w) };
            *(uint2*)&sT[r * 68 + d]     = u0;
            *(uint2*)&sT[r * 68 + d + 4] = u1;
        }
        __syncthreads();
        #pragma unroll
        for (int p = 0; p < 4; ++p) {
            int d = p * 16 + (tid >> 4);
            int c = tid & 15;
            unsigned v[4];
            #pragma unroll
            for (int j = 0; j < 4; ++j) {
                unsigned lo = sT[(c * 8 + 2 * j) * 68 + d];
                unsigned hi = sT[(c * 8 + 2 * j + 1) * 68 + d];
                v[j] = lo | (hi << 16);
            }
            uint4 u = { v[0], v[1], v[2], v[3] };
            *(uint4*)&Vt[((size_t)(bh * HD + d)) * SL + k0 + c * 8] = u;
        }
    } else {
        int t = bid - 3072;
        int lane = tid & 63;
        #pragma unroll
        for (int r = 0; r < 4; ++r) {
            int wid = (t * 4 + (tid >> 6)) * 4 + r;
            int c = wid & 15, q = (wid >> 4) & 1023, bb = wid >> 14;
            int mv = mask[((size_t)bb * SL + q) * SL + c * 64 + lane];
            unsigned long long bits = __ballot(mv != 0);
            if (lane == 0) Mbt[((size_t)bb * 16 + c) * SL + q] = bits;
        }
    }
}

// ---------------- Flash attention v9: barrier-free, LDS-free ----------------
// Every MFMA fragment is a contiguous 16B/lane chunk in the prepared global
// layouts (Kb[bh][k][d], Vt[bh][d][k]) -> load fragments straight to VGPRs.
// No LDS, no __syncthreads, no gload_lds: each wave free-runs. K frags
// register-double-buffered one tile ahead (kA/kB, unroll x2); V frags issued
// at tile start, consumed after QK+softmax blob (~300cy cover); mask word
// prefetched one tile ahead. All 4 waves of a block read identical K/V
// addresses -> L1 absorbs the redundancy; 8 bh per XCD (2MB) stays in L2.
// Compiler inserts precise counted vmcnt waits; issue order pinned with
// MEMPIN + one sched_barrier(0) per tile. launch_bounds(256,3): LDS=0, so
// occupancy is VGPR-limited -> 12 waves/CU.
#define TILE(KT, KC, KN)                                                       \
{                                                                              \
    const int kt_ = (KT);                                                      \
    {                                                                          \
        const unsigned short* vp = Vp + kt_ * 64;                              \
        _Pragma("unroll")                                                      \
        for (int dt = 0; dt < 4; ++dt) {                                       \
            vC[2*dt]   = *(const bf16x8*)&vp[(dt*16 + m16) * SL + quad * 8];   \
            vC[2*dt+1] = *(const bf16x8*)&vp[(dt*16 + m16) * SL + (4+quad)*8]; \
        }                                                                      \
    }                                                                          \
    MEMPIN();                                                                  \
    if (kt_ < 15) {                                                            \
        const unsigned short* kp = Kp + (size_t)(kt_ + 1) * 64 * HD;           \
        _Pragma("unroll")                                                      \
        for (int t = 0; t < 4; ++t) {                                          \
            KN[2*t]   = *(const bf16x8*)&kp[(t*16 + m16) * HD + quad * 8];     \
            KN[2*t+1] = *(const bf16x8*)&kp[(t*16 + m16) * HD + (4+quad)*8];   \
        }                                                                      \
        MEMPIN();                                                              \
        mbB = Mp[(size_t)(kt_ + 1) * SL];                                      \
        MEMPIN();                                                              \
    }                                                                          \
    __builtin_amdgcn_sched_barrier(0);                                         \
    f32x4 sc[4];                                                               \
    __builtin_amdgcn_s_setprio(1);                                             \
    _Pragma("unroll")                                                          \
    for (int t = 0; t < 4; ++t) {                                              \
        f32x4 z = {0.f, 0.f, 0.f, 0.f};                                        \
        sc[t] = __builtin_amdgcn_mfma_f32_16x16x32_bf16(KC[2*t],   bQ[0], z,     0,0,0); \
        sc[t] = __builtin_amdgcn_mfma_f32_16x16x32_bf16(KC[2*t+1], bQ[1], sc[t], 0,0,0); \
    }                                                                          \
    __builtin_amdgcn_s_setprio(0);                                             \
    bf16x8 bP[2];                                                              \
    {                                                                          \
        unsigned mlo = (unsigned)mbA, mhi = (unsigned)(mbA >> 32);             \
        unsigned s0 = mlo >> (quad * 8);                                       \
        unsigned s1 = mhi >> (quad * 8);                                       \
        unsigned wt[4][2];                                                     \
        _Pragma("unroll")                                                      \
        for (int t = 0; t < 4; ++t) {                                          \
            wt[t][0] = pk2(exp2_fast(sc[t][0] * CSC), exp2_fast(sc[t][1] * CSC)); \
            wt[t][1] = pk2(exp2_fast(sc[t][2] * CSC), exp2_fast(sc[t][3] * CSC)); \
        }                                                                      \
        unsigned g[2][4];                                                      \
        _Pragma("unroll")                                                      \
        for (int hh = 0; hh < 2; ++hh) {                                       \
            _Pragma("unroll")                                                  \
            for (int p = 0; p < 2; ++p) {                                      \
                unsigned A = wt[2*hh][p], B = wt[2*hh+1][p];                   \
                asm("v_permlane32_swap_b32 %0, %1" : "+v"(A), "+v"(B));        \
                asm("v_permlane16_swap_b32 %0, %1" : "+v"(A), "+v"(B));        \
                g[hh][p] = A; g[hh][2+p] = B;                                  \
            }                                                                  \
        }                                                                      \
        _Pragma("unroll")                                                      \
        for (int hh = 0; hh < 2; ++hh) {                                       \
            unsigned sb = hh ? s1 : s0;                                        \
            _Pragma("unroll")                                                  \
            for (int j2 = 0; j2 < 4; ++j2) {                                   \
                unsigned b2 = (sb >> (2*j2)) & 3u;                             \
                unsigned am = ((b2 & 1u) ? 0xFFFFu : 0u) | ((b2 & 2u) ? 0xFFFF0000u : 0u); \
                g[hh][j2] &= am;                                               \
            }                                                                  \
        }                                                                      \
        u32x4 p0 = { g[0][0], g[0][1], g[0][2], g[0][3] };                     \
        u32x4 p1 = { g[1][0], g[1][1], g[1][2], g[1][3] };                     \
        bP[0] = __builtin_bit_cast(bf16x8, p0);                                \
        bP[1] = __builtin_bit_cast(bf16x8, p1);                                \
    }                                                                          \
    __builtin_amdgcn_s_setprio(1);                                             \
    lacc = __builtin_amdgcn_mfma_f32_16x16x32_bf16(ones, bP[0], lacc, 0,0,0);  \
    lacc = __builtin_amdgcn_mfma_f32_16x16x32_bf16(ones, bP[1], lacc, 0,0,0);  \
    _Pragma("unroll")                                                          \
    for (int dt = 0; dt < 4; ++dt) {                                           \
        O[dt] = __builtin_amdgcn_mfma_f32_16x16x32_bf16(vC[2*dt],   bP[0], O[dt], 0,0,0); \
        O[dt] = __builtin_amdgcn_mfma_f32_16x16x32_bf16(vC[2*dt+1], bP[1], O[dt], 0,0,0); \
    }                                                                          \
    __builtin_amdgcn_s_setprio(0);                                             \
    mbA = mbB;                                                                 \
}

__global__ __launch_bounds__(256, 3) void attn_mfma(
    const float* __restrict__ Q, const unsigned short* __restrict__ Kb,
    const unsigned short* __restrict__ Vt,
    const unsigned long long* __restrict__ Mbt,
    unsigned short* __restrict__ Oa)
{
    const int lin = blockIdx.x;
    const int xcd = lin & 7, slot = lin >> 3;
    const int bh = xcd * 8 + (slot >> 4);       // 8 bh per XCD
    const int q0 = (slot & 15) * QB;            // 16 q-tiles of that bh
    const int b = bh >> 4, h = bh & 15;
    const int tid = threadIdx.x;
    const int w = tid >> 6, lane = tid & 63;
    const int m16 = lane & 15, quad = lane >> 4;

    const unsigned short* Kp = Kb + (size_t)bh * SL * HD;            // [k][d]
    const unsigned short* Vp = Vt + (size_t)bh * HD * SL;            // [d][k]
    const unsigned long long* Mp = Mbt + (size_t)(b * 16) * SL + q0 + w * 16 + m16;

    // --- prologue: bQ in-register from f32 Q, then K tile0 + mask word ---
    bf16x8 bQ[2];
    {
        const float* qp = &Q[((size_t)(b * SL + q0 + w * 16 + m16)) * EMB + h * HD + quad * 8];
        float4 f0 = *(const float4*)qp,        f1 = *(const float4*)(qp + 4);
        float4 f2 = *(const float4*)(qp + 32), f3 = *(const float4*)(qp + 36);
        u32x4 u0 = { pk2(f0.x,f0.y), pk2(f0.z,f0.w), pk2(f1.x,f1.y), pk2(f1.z,f1.w) };
        u32x4 u1 = { pk2(f2.x,f2.y), pk2(f2.z,f2.w), pk2(f3.x,f3.y), pk2(f3.z,f3.w) };
        bQ[0] = __builtin_bit_cast(bf16x8, u0);
        bQ[1] = __builtin_bit_cast(bf16x8, u1);
    }
    MEMPIN();
    bf16x8 kA[8], kB[8], vC[8];
    unsigned long long mbA, mbB = 0;
    #pragma unroll
    for (int t = 0; t < 4; ++t) {
        kA[2*t]   = *(const bf16x8*)&Kp[(t*16 + m16) * HD + quad * 8];
        kA[2*t+1] = *(const bf16x8*)&Kp[(t*16 + m16) * HD + (4+quad)*8];
    }
    MEMPIN();
    mbA = Mp[0];
    MEMPIN();

    f32x4 O[4] = {};
    f32x4 lacc = {};
    const float CSC = 0.125f * 1.44269504f;
    const short one_bf = (short)0x3F80;
    const bf16x8 ones = { one_bf, one_bf, one_bf, one_bf, one_bf, one_bf, one_bf, one_bf };

    for (int i = 0; i < 8; ++i) {
        TILE(2*i,     kA, kB)
        TILE(2*i + 1, kB, kA)
    }

    // epilogue: per-lane l (col q = m16), normalize, store bf16
    {
        float inv = 1.f / lacc[0];
        size_t base = ((size_t)(b * SL + q0 + w * 16 + m16)) * EMB + h * HD + quad * 4;
        #pragma unroll
        for (int dt = 0; dt < 4; ++dt) {
            uint2 ow = { pk2(O[dt][0] * inv, O[dt][1] * inv),
                         pk2(O[dt][2] * inv, O[dt][3] * inv) };
            *(uint2*)&Oa[base + dt * 16] = ow;
        }
    }
}

// ---------------- Projection: C[4096][1024] = A_bf16 @ W_bf16^T + bias ----------------
__global__ __launch_bounds__(512, 2) void proj_mfma(
    const unsigned short* __restrict__ A, const unsigned short* __restrict__ Wb,
    const float* __restrict__ bias, float* __restrict__ C)
{
    const int n0 = blockIdx.x * 128;
    const int m0 = blockIdx.y * 128;
    const int tid = threadIdx.x;
    const int w = tid >> 6, lane = tid & 63;
    const int m16 = lane & 15, quad = lane >> 4;
    const int lr = lane >> 3, lc = lane & 7;
    const int wm = (w >> 2) * 64, wn = (w & 3) * 32;

    __shared__ __align__(16) unsigned short sA[2][128 * 64];
    __shared__ __align__(16) unsigned short sW[2][128 * 64];

    f32x4 acc[4][2] = {};

    #pragma unroll
    for (int i = 0; i < 2; ++i) {
        int r = w * 16 + i * 8;
        gload_lds16(&A [(size_t)(m0 + r + lr) * EMB + (lc ^ lr) * 8], &sA[0][r * 64]);
        gload_lds16(&Wb[(size_t)(n0 + r + lr) * EMB + (lc ^ lr) * 8], &sW[0][r * 64]);
    }
    __syncthreads();

    for (int it = 0; it < 16; ++it) {
        const int bf = it & 1;
        if (it < 15) {
            int e0 = (it + 1) * 64;
            #pragma unroll
            for (int i = 0; i < 2; ++i) {
                int r = w * 16 + i * 8;
                gload_lds16(&A [(size_t)(m0 + r + lr) * EMB + e0 + (lc ^ lr) * 8], &sA[bf ^ 1][r * 64]);
                gload_lds16(&Wb[(size_t)(n0 + r + lr) * EMB + e0 + (lc ^ lr) * 8], &sW[bf ^ 1][r * 64]);
            }
        }
        #pragma unroll
        for (int hh = 0; hh < 2; ++hh) {
            bf16x8 af[4], bw[2];
            #pragma unroll
            for (int mt = 0; mt < 4; ++mt) {
                int r = wm + mt * 16 + m16;
                af[mt] = *(const bf16x8*)&sA[bf][r * 64 + (((hh * 4 + quad) ^ (r & 7)) * 8)];
            }
            #pragma unroll
            for (int nt = 0; nt < 2; ++nt) {
                int r = wn + nt * 16 + m16;
                bw[nt] = *(const bf16x8*)&sW[bf][r * 64 + (((hh * 4 + quad) ^ (r & 7)) * 8)];
            }
            #pragma unroll
            for (int mt = 0; mt < 4; ++mt)
                #pragma unroll
                for (int nt = 0; nt < 2; ++nt)
                    acc[mt][nt] = __builtin_amdgcn_mfma_f32_16x16x32_bf16(af[mt], bw[nt], acc[mt][nt], 0,0,0);
        }
        __syncthreads();
    }

    #pragma unroll
    for (int nt = 0; nt < 2; ++nt) {
        float bv = bias[n0 + wn + nt * 16 + m16];
        #pragma unroll
        for (int mt = 0; mt < 4; ++mt) {
            size_t row = (size_t)(m0 + wm + mt * 16 + quad * 4);
            #pragma unroll
            for (int rg = 0; rg < 4; ++rg)
                C[(row + rg) * EMB + n0 + wn + nt * 16 + m16] = acc[mt][nt][rg] + bv;
        }
    }
}

extern "C" void kernel_launch(void* const* d_in, const int* in_sizes, int n_in,
                              void* d_out, int out_size, void* d_ws, size_t ws_size,
                              hipStream_t stream) {
    const float* Q    = (const float*)d_in[0];
    const float* K    = (const float*)d_in[1];
    const float* V    = (const float*)d_in[2];
    const int*   mask = (const int*)  d_in[3];
    const float* W    = (const float*)d_in[4];
    const float* bias = (const float*)d_in[5];

    unsigned short* Oa = (unsigned short*)d_ws;                              // 8.39 MB
    unsigned short* Wb = Oa + (size_t)NB * SL * EMB;                         // 2.10 MB
    unsigned long long* Mbt = (unsigned long long*)(Wb + (size_t)EMB * EMB); // 0.52 MB
    unsigned short* Vt = (unsigned short*)(Mbt + (size_t)NB * 16 * SL);      // 8.39 MB
    unsigned short* Kb = Vt + (size_t)NB * NH * HD * SL;                     // 8.39 MB

    prep<<<7168, 256, 0, stream>>>(W, Wb, K, Kb, V, Vt, mask, Mbt);
    attn_mfma<<<1024, 256, 0, stream>>>(Q, Kb, Vt, Mbt, Oa);
    proj_mfma<<<dim3(EMB / 128, (NB * SL) / 128), 512, 0, stream>>>(Oa, Wb, bias, (float*)d_out);
}

// Round 5
// 162.123 us; speedup vs baseline: 1.5646x; 1.5646x over previous
//
#include <hip/hip_runtime.h>
#include <math.h>

#define NB 4
#define SL 1024
#define EMB 1024
#define NH 16
#define HD 64
#define QB 128

typedef __attribute__((ext_vector_type(8))) short bf16x8;
typedef __attribute__((ext_vector_type(4))) float f32x4;
typedef __attribute__((ext_vector_type(4))) unsigned u32x4;

// round-half-up f32->bf16 pack (inputs finite)
static __device__ __forceinline__ unsigned pk2(float a, float b) {
    unsigned x = __float_as_uint(a) + 0x8000u;
    unsigned y = __float_as_uint(b) + 0x8000u;
    return (x >> 16) | (y & 0xFFFF0000u);
}
static __device__ __forceinline__ float exp2_fast(float x) {
    float r; asm("v_exp_f32 %0, %1" : "=v"(r) : "v"(x)); return r;
}
static __device__ __forceinline__ void gload_lds16(const void* g, void* l) {
    __builtin_amdgcn_global_load_lds(
        (const __attribute__((address_space(1))) unsigned int*)g,
        (__attribute__((address_space(3))) unsigned int*)l, 16, 0, 0);
}

#define VMW(n) asm volatile("s_waitcnt vmcnt(" #n ")" ::: "memory")
#define MEMPIN() asm volatile("" ::: "memory")

// ---------------- Fused prep: W conv | K conv+split | V transpose | mask bitmask ----------------
__global__ __launch_bounds__(256) void prep(
    const float* __restrict__ W, unsigned short* __restrict__ Wb,
    const float* __restrict__ Kf, unsigned short* __restrict__ Kb,
    const float* __restrict__ V, unsigned short* __restrict__ Vt,
    const int* __restrict__ mask, unsigned long long* __restrict__ Mbt)
{
    __shared__ unsigned short sT[128 * 68];
    const int bid = blockIdx.x, tid = threadIdx.x;

    if (bid < 512) {
        int i = (bid * 256 + tid) * 8;
        float4 f0 = *(const float4*)&W[i];
        float4 f1 = *(const float4*)&W[i + 4];
        uint4 u = { pk2(f0.x,f0.y), pk2(f0.z,f0.w), pk2(f1.x,f1.y), pk2(f1.z,f1.w) };
        *(uint4*)&Wb[i] = u;
    } else if (bid < 2560) {
        int t = bid - 512;
        int b = t >> 9, h = (t >> 5) & 15, k0 = (t & 31) * 32;
        int r = tid >> 3, d = (tid & 7) * 8;
        const float* gp = &Kf[((size_t)(b * SL + k0 + r)) * EMB + h * HD + d];
        float4 f0 = *(const float4*)gp, f1 = *(const float4*)(gp + 4);
        uint4 u = { pk2(f0.x,f0.y), pk2(f0.z,f0.w), pk2(f1.x,f1.y), pk2(f1.z,f1.w) };
        *(uint4*)&Kb[((size_t)((b * NH + h) * SL + k0 + r)) * HD + d] = u;
    } else if (bid < 3072) {
        int t = bid - 2560;
        int bh = t >> 3, kb = t & 7;
        int b = bh >> 4, h = bh & 15;
        int k0 = kb * 128;
        #pragma unroll
        for (int i = 0; i < 4; ++i) {
            int lin = (i * 256 + tid) * 8;
            int r = lin >> 6, d = lin & 63;
            const float* gp = &V[((size_t)(b * SL + k0 + r)) * EMB + h * HD + d];
            float4 f0 = *(const float4*)gp, f1 = *(const float4*)(gp + 4);
            uint2 u0 = { pk2(f0.x,f0.y), pk2(f0.z,f0.w) };
            uint2 u1 = { pk2(f1.x,f1.y), pk2(f1.z,f1.w) };
            *(uint2*)&sT[r * 68 + d]     = u0;
            *(uint2*)&sT[r * 68 + d + 4] = u1;
        }
        __syncthreads();
        #pragma unroll
        for (int p = 0; p < 4; ++p) {
            int d = p * 16 + (tid >> 4);
            int c = tid & 15;
            unsigned v[4];
            #pragma unroll
            for (int j = 0; j < 4; ++j) {
                unsigned lo = sT[(c * 8 + 2 * j) * 68 + d];
                unsigned hi = sT[(c * 8 + 2 * j + 1) * 68 + d];
                v[j] = lo | (hi << 16);
            }
            uint4 u = { v[0], v[1], v[2], v[3] };
            *(uint4*)&Vt[((size_t)(bh * HD + d)) * SL + k0 + c * 8] = u;
        }
    } else {
        int t = bid - 3072;
        int lane = tid & 63;
        #pragma unroll
        for (int r = 0; r < 4; ++r) {
            int wid = (t * 4 + (tid >> 6)) * 4 + r;
            int c = wid & 15, q = (wid >> 4) & 1023, bb = wid >> 14;
            int mv = mask[((size_t)bb * SL + q) * SL + c * 64 + lane];
            unsigned long long bits = __ballot(mv != 0);
            if (lane == 0) Mbt[((size_t)bb * 16 + c) * SL + q] = bits;
        }
    }
}

// ---------------- Flash attention v10: 8-wave blocks, LDS K/V, in-reg P ----------------
// 512 threads (8 waves), QB=128, each wave owns 16 q-rows. LDS = 3-buffer
// K/V only (48 KB) -> 2 blocks/CU = 16 waves/CU (4/SIMD, double the old TLP).
// Staging split across 8 waves: 1 K + 1 V gload_lds + 1 mask word per wave
// per tile; counted vmcnt(4) (tail vmcnt(1)), one s_barrier per tile.
// P never touches LDS (permlane32/16_swap redistribution, proven R2-R4).
// Q packed in-register from f32 in prologue. XCD map: 8 bh per XCD.
__global__ __launch_bounds__(512, 4) void attn_mfma(
    const float* __restrict__ Q, const unsigned short* __restrict__ Kb,
    const unsigned short* __restrict__ Vt,
    const unsigned long long* __restrict__ Mbt,
    unsigned short* __restrict__ Oa)
{
    const int lin = blockIdx.x;
    const int xcd = lin & 7, slot = lin >> 3;
    const int bh = xcd * 8 + (slot >> 3);       // 8 bh per XCD
    const int q0 = (slot & 7) * QB;             // 8 q-tiles of that bh
    const int b = bh >> 4, h = bh & 15;
    const int tid = threadIdx.x;
    const int w = tid >> 6, lane = tid & 63;
    const int m16 = lane & 15, quad = lane >> 4;
    const int lr = lane >> 3, lc = lane & 7;
    const int srow = w * 8;                     // this wave's staging row base

    __shared__ __align__(16) unsigned short sK[3][64 * 64];
    __shared__ __align__(16) unsigned short sVt[3][64 * 64];

    const size_t vbase = (size_t)(bh * HD) * SL;   // Vt row d, len SL
    const size_t kbase = (size_t)(bh * SL) * HD;   // Kb row k, len 64
    const unsigned long long* Mp = Mbt + (size_t)(b * 16) * SL + q0 + w * 16 + m16;

    // --- prologue: Q loads first (oldest vmem, retired at bQ pack) ---
    const float* qp = &Q[((size_t)(b * SL + q0 + w * 16 + m16)) * EMB + h * HD + quad * 8];
    float4 f0 = *(const float4*)qp,        f1 = *(const float4*)(qp + 4);
    float4 f2 = *(const float4*)(qp + 32), f3 = *(const float4*)(qp + 36);
    MEMPIN();
    // stage tile0 {V,K}, mb(0); stage tile1 {V,K}, mb(1)  (order pinned)
    unsigned long long mbA, mbB, mbC = 0;
    gload_lds16(&Vt[vbase + (size_t)(srow + lr) * SL + (lc ^ lr) * 8], &sVt[0][srow * 64]);
    gload_lds16(&Kb[kbase + (size_t)(srow + lr) * HD + (lc ^ lr) * 8], &sK[0][srow * 64]);
    MEMPIN();
    mbA = Mp[0];
    MEMPIN();
    gload_lds16(&Vt[vbase + (size_t)(srow + lr) * SL + 64 + (lc ^ lr) * 8], &sVt[1][srow * 64]);
    gload_lds16(&Kb[kbase + (size_t)(64 + srow + lr) * HD + (lc ^ lr) * 8], &sK[1][srow * 64]);
    MEMPIN();
    mbB = Mp[SL];
    MEMPIN();

    // pack bQ (compiler waits only on the Q loads)
    bf16x8 bQ[2];
    {
        u32x4 u0 = { pk2(f0.x,f0.y), pk2(f0.z,f0.w), pk2(f1.x,f1.y), pk2(f1.z,f1.w) };
        u32x4 u1 = { pk2(f2.x,f2.y), pk2(f2.z,f2.w), pk2(f3.x,f3.y), pk2(f3.z,f3.w) };
        bQ[0] = __builtin_bit_cast(bf16x8, u0);
        bQ[1] = __builtin_bit_cast(bf16x8, u1);
    }

    unsigned short* kc = (unsigned short*)sK[0];
    unsigned short* kn = (unsigned short*)sK[1];
    unsigned short* k2 = (unsigned short*)sK[2];
    unsigned short* vc = (unsigned short*)sVt[0];
    unsigned short* vn = (unsigned short*)sVt[1];
    unsigned short* v2 = (unsigned short*)sVt[2];

    f32x4 O[4] = {};
    f32x4 lacc = {};
    const float CSC = 0.125f * 1.44269504f;
    const short one_bf = (short)0x3F80;
    const bf16x8 ones = { one_bf, one_bf, one_bf, one_bf, one_bf, one_bf, one_bf, one_bf };

    for (int kt = 0; kt < 16; ++kt) {
        // issue order/tile: [gV, gK, mb]. At tile kt top, newer than gK(kt):
        // mb(kt), gV(kt+1), gK(kt+1), mb(kt+1) = 4  -> VMW(4); tail VMW(1).
        if (kt < 15) { VMW(4); } else { VMW(1); }
        __builtin_amdgcn_s_barrier();
        __builtin_amdgcn_sched_barrier(0);

        if (kt < 14) {
            const int k0n = (kt + 2) * 64;
            gload_lds16(&Vt[vbase + (size_t)(srow + lr) * SL + k0n + (lc ^ lr) * 8],
                        &v2[srow * 64]);
            gload_lds16(&Kb[kbase + (size_t)(k0n + srow + lr) * HD + (lc ^ lr) * 8],
                        &k2[srow * 64]);
            MEMPIN();   // keep mb load AFTER the gloads (vmcnt arithmetic)
            mbC = Mp[(size_t)(kt + 2) * SL];
            MEMPIN();
        }

        // scores: S^T[64k][16q]
        f32x4 sc[4];
        __builtin_amdgcn_s_setprio(1);
        #pragma unroll
        for (int t = 0; t < 4; ++t) {
            int krow = t * 16 + m16;
            bf16x8 a0 = *(const bf16x8*)&kc[krow * 64 + ((quad ^ (krow & 7)) * 8)];
            bf16x8 a1 = *(const bf16x8*)&kc[krow * 64 + (((4 + quad) ^ (krow & 7)) * 8)];
            f32x4 z = {0.f, 0.f, 0.f, 0.f};
            sc[t] = __builtin_amdgcn_mfma_f32_16x16x32_bf16(a0, bQ[0], z,     0,0,0);
            sc[t] = __builtin_amdgcn_mfma_f32_16x16x32_bf16(a1, bQ[1], sc[t], 0,0,0);
        }
        __builtin_amdgcn_s_setprio(0);

        // exp2 (fixed shift) + in-register redistribution to PV B-frag layout.
        // source lane (q=m16, quad): k = t*16 + quad*4 + reg (packed pairs)
        // target lane (q=m16, quad): k = hh*32 + quad*8 + j   (bf16x8 frag)
        bf16x8 bP[2];
        {
            unsigned mlo = (unsigned)mbA, mhi = (unsigned)(mbA >> 32);
            unsigned s0 = mlo >> (quad * 8);
            unsigned s1 = mhi >> (quad * 8);
            unsigned wt[4][2];
            #pragma unroll
            for (int t = 0; t < 4; ++t) {
                wt[t][0] = pk2(exp2_fast(sc[t][0] * CSC), exp2_fast(sc[t][1] * CSC));
                wt[t][1] = pk2(exp2_fast(sc[t][2] * CSC), exp2_fast(sc[t][3] * CSC));
            }
            unsigned g[2][4];
            #pragma unroll
            for (int hh = 0; hh < 2; ++hh)
                #pragma unroll
                for (int p = 0; p < 2; ++p) {
                    unsigned A = wt[2 * hh][p], B = wt[2 * hh + 1][p];
                    asm("v_permlane32_swap_b32 %0, %1" : "+v"(A), "+v"(B));
                    asm("v_permlane16_swap_b32 %0, %1" : "+v"(A), "+v"(B));
                    g[hh][p] = A; g[hh][2 + p] = B;
                }
            #pragma unroll
            for (int hh = 0; hh < 2; ++hh) {
                unsigned sb = hh ? s1 : s0;
                #pragma unroll
                for (int j2 = 0; j2 < 4; ++j2) {
                    unsigned b2 = (sb >> (2 * j2)) & 3u;
                    unsigned am = ((b2 & 1u) ? 0xFFFFu : 0u) | ((b2 & 2u) ? 0xFFFF0000u : 0u);
                    g[hh][j2] &= am;
                }
            }
            u32x4 p0 = { g[0][0], g[0][1], g[0][2], g[0][3] };
            u32x4 p1 = { g[1][0], g[1][1], g[1][2], g[1][3] };
            bP[0] = __builtin_bit_cast(bf16x8, p0);
            bP[1] = __builtin_bit_cast(bf16x8, p1);
        }

        __builtin_amdgcn_s_setprio(1);
        // l accumulation: lacc += 1^T P
        lacc = __builtin_amdgcn_mfma_f32_16x16x32_bf16(ones, bP[0], lacc, 0,0,0);
        lacc = __builtin_amdgcn_mfma_f32_16x16x32_bf16(ones, bP[1], lacc, 0,0,0);

        // PV: O^T[64d][16q] += V^T P
        #pragma unroll
        for (int dt = 0; dt < 4; ++dt) {
            int drow = dt * 16 + m16;
            bf16x8 v0 = *(const bf16x8*)&vc[drow * 64 + ((quad ^ (drow & 7)) * 8)];
            bf16x8 v1 = *(const bf16x8*)&vc[drow * 64 + (((4 + quad) ^ (drow & 7)) * 8)];
            O[dt] = __builtin_amdgcn_mfma_f32_16x16x32_bf16(v0, bP[0], O[dt], 0,0,0);
            O[dt] = __builtin_amdgcn_mfma_f32_16x16x32_bf16(v1, bP[1], O[dt], 0,0,0);
        }
        __builtin_amdgcn_s_setprio(0);

        // rotate buffers + mask shift registers
        unsigned short* tk = kc; kc = kn; kn = k2; k2 = tk;
        unsigned short* tv = vc; vc = vn; vn = v2; v2 = tv;
        mbA = mbB; mbB = mbC;
    }

    // epilogue: per-lane l (col q = m16), normalize, store bf16
    {
        float inv = 1.f / lacc[0];
        size_t base = ((size_t)(b * SL + q0 + w * 16 + m16)) * EMB + h * HD + quad * 4;
        #pragma unroll
        for (int dt = 0; dt < 4; ++dt) {
            uint2 ow = { pk2(O[dt][0] * inv, O[dt][1] * inv),
                         pk2(O[dt][2] * inv, O[dt][3] * inv) };
            *(uint2*)&Oa[base + dt * 16] = ow;
        }
    }
}

// ---------------- Projection: C[4096][1024] = A_bf16 @ W_bf16^T + bias ----------------
__global__ __launch_bounds__(512, 2) void proj_mfma(
    const unsigned short* __restrict__ A, const unsigned short* __restrict__ Wb,
    const float* __restrict__ bias, float* __restrict__ C)
{
    const int n0 = blockIdx.x * 128;
    const int m0 = blockIdx.y * 128;
    const int tid = threadIdx.x;
    const int w = tid >> 6, lane = tid & 63;
    const int m16 = lane & 15, quad = lane >> 4;
    const int lr = lane >> 3, lc = lane & 7;
    const int wm = (w >> 2) * 64, wn = (w & 3) * 32;

    __shared__ __align__(16) unsigned short sA[2][128 * 64];
    __shared__ __align__(16) unsigned short sW[2][128 * 64];

    f32x4 acc[4][2] = {};

    #pragma unroll
    for (int i = 0; i < 2; ++i) {
        int r = w * 16 + i * 8;
        gload_lds16(&A [(size_t)(m0 + r + lr) * EMB + (lc ^ lr) * 8], &sA[0][r * 64]);
        gload_lds16(&Wb[(size_t)(n0 + r + lr) * EMB + (lc ^ lr) * 8], &sW[0][r * 64]);
    }
    __syncthreads();

    for (int it = 0; it < 16; ++it) {
        const int bf = it & 1;
        if (it < 15) {
            int e0 = (it + 1) * 64;
            #pragma unroll
            for (int i = 0; i < 2; ++i) {
                int r = w * 16 + i * 8;
                gload_lds16(&A [(size_t)(m0 + r + lr) * EMB + e0 + (lc ^ lr) * 8], &sA[bf ^ 1][r * 64]);
                gload_lds16(&Wb[(size_t)(n0 + r + lr) * EMB + e0 + (lc ^ lr) * 8], &sW[bf ^ 1][r * 64]);
            }
        }
        #pragma unroll
        for (int hh = 0; hh < 2; ++hh) {
            bf16x8 af[4], bw[2];
            #pragma unroll
            for (int mt = 0; mt < 4; ++mt) {
                int r = wm + mt * 16 + m16;
                af[mt] = *(const bf16x8*)&sA[bf][r * 64 + (((hh * 4 + quad) ^ (r & 7)) * 8)];
            }
            #pragma unroll
            for (int nt = 0; nt < 2; ++nt) {
                int r = wn + nt * 16 + m16;
                bw[nt] = *(const bf16x8*)&sW[bf][r * 64 + (((hh * 4 + quad) ^ (r & 7)) * 8)];
            }
            #pragma unroll
            for (int mt = 0; mt < 4; ++mt)
                #pragma unroll
                for (int nt = 0; nt < 2; ++nt)
                    acc[mt][nt] = __builtin_amdgcn_mfma_f32_16x16x32_bf16(af[mt], bw[nt], acc[mt][nt], 0,0,0);
        }
        __syncthreads();
    }

    #pragma unroll
    for (int nt = 0; nt < 2; ++nt) {
        float bv = bias[n0 + wn + nt * 16 + m16];
        #pragma unroll
        for (int mt = 0; mt < 4; ++mt) {
            size_t row = (size_t)(m0 + wm + mt * 16 + quad * 4);
            #pragma unroll
            for (int rg = 0; rg < 4; ++rg)
                C[(row + rg) * EMB + n0 + wn + nt * 16 + m16] = acc[mt][nt][rg] + bv;
        }
    }
}

extern "C" void kernel_launch(void* const* d_in, const int* in_sizes, int n_in,
                              void* d_out, int out_size, void* d_ws, size_t ws_size,
                              hipStream_t stream) {
    const float* Q    = (const float*)d_in[0];
    const float* K    = (const float*)d_in[1];
    const float* V    = (const float*)d_in[2];
    const int*   mask = (const int*)  d_in[3];
    const float* W    = (const float*)d_in[4];
    const float* bias = (const float*)d_in[5];

    unsigned short* Oa = (unsigned short*)d_ws;                              // 8.39 MB
    unsigned short* Wb = Oa + (size_t)NB * SL * EMB;                         // 2.10 MB
    unsigned long long* Mbt = (unsigned long long*)(Wb + (size_t)EMB * EMB); // 0.52 MB
    unsigned short* Vt = (unsigned short*)(Mbt + (size_t)NB * 16 * SL);      // 8.39 MB
    unsigned short* Kb = Vt + (size_t)NB * NH * HD * SL;                     // 8.39 MB

    prep<<<7168, 256, 0, stream>>>(W, Wb, K, Kb, V, Vt, mask, Mbt);
    attn_mfma<<<512, 512, 0, stream>>>(Q, Kb, Vt, Mbt, Oa);
    proj_mfma<<<dim3(EMB / 128, (NB * SL) / 128), 512, 0, stream>>>(Oa, Wb, bias, (float*)d_out);
}

// Round 6
// 159.984 us; speedup vs baseline: 1.5855x; 1.0134x over previous
//
#include <hip/hip_runtime.h>
#include <math.h>

#define NB 4
#define SL 1024
#define EMB 1024
#define NH 16
#define HD 64
#define QB 128

typedef __attribute__((ext_vector_type(8))) short bf16x8;
typedef __attribute__((ext_vector_type(4))) float f32x4;
typedef __attribute__((ext_vector_type(4))) unsigned u32x4;

// round-half-up f32->bf16 pack (inputs finite)
static __device__ __forceinline__ unsigned pk2(float a, float b) {
    unsigned x = __float_as_uint(a) + 0x8000u;
    unsigned y = __float_as_uint(b) + 0x8000u;
    return (x >> 16) | (y & 0xFFFF0000u);
}
static __device__ __forceinline__ float exp2_fast(float x) {
    float r; asm("v_exp_f32 %0, %1" : "=v"(r) : "v"(x)); return r;
}
// 2x f32 -> packed bf16 (RNE), single instruction
static __device__ __forceinline__ unsigned cvtpk(float a, float b) {
    unsigned r; asm("v_cvt_pk_bf16_f32 %0, %1, %2" : "=v"(r) : "v"(a), "v"(b)); return r;
}
static __device__ __forceinline__ void gload_lds16(const void* g, void* l) {
    __builtin_amdgcn_global_load_lds(
        (const __attribute__((address_space(1))) unsigned int*)g,
        (__attribute__((address_space(3))) unsigned int*)l, 16, 0, 0);
}

#define VMW(n) asm volatile("s_waitcnt vmcnt(" #n ")" ::: "memory")
#define MEMPIN() asm volatile("" ::: "memory")

// ---------------- Fused prep: W conv | K conv+split (xCSC) | V transpose | mask bitmask ----------------
__global__ __launch_bounds__(256) void prep(
    const float* __restrict__ W, unsigned short* __restrict__ Wb,
    const float* __restrict__ Kf, unsigned short* __restrict__ Kb,
    const float* __restrict__ V, unsigned short* __restrict__ Vt,
    const int* __restrict__ mask, unsigned long long* __restrict__ Mbt)
{
    __shared__ unsigned short sT[128 * 68];
    const int bid = blockIdx.x, tid = threadIdx.x;
    const float CSC = 0.125f * 1.44269504f;   // folded into K so scores are exp2-ready

    if (bid < 512) {
        int i = (bid * 256 + tid) * 8;
        float4 f0 = *(const float4*)&W[i];
        float4 f1 = *(const float4*)&W[i + 4];
        uint4 u = { pk2(f0.x,f0.y), pk2(f0.z,f0.w), pk2(f1.x,f1.y), pk2(f1.z,f1.w) };
        *(uint4*)&Wb[i] = u;
    } else if (bid < 2560) {
        int t = bid - 512;
        int b = t >> 9, h = (t >> 5) & 15, k0 = (t & 31) * 32;
        int r = tid >> 3, d = (tid & 7) * 8;
        const float* gp = &Kf[((size_t)(b * SL + k0 + r)) * EMB + h * HD + d];
        float4 f0 = *(const float4*)gp, f1 = *(const float4*)(gp + 4);
        uint4 u = { pk2(f0.x*CSC,f0.y*CSC), pk2(f0.z*CSC,f0.w*CSC),
                    pk2(f1.x*CSC,f1.y*CSC), pk2(f1.z*CSC,f1.w*CSC) };
        *(uint4*)&Kb[((size_t)((b * NH + h) * SL + k0 + r)) * HD + d] = u;
    } else if (bid < 3072) {
        int t = bid - 2560;
        int bh = t >> 3, kb = t & 7;
        int b = bh >> 4, h = bh & 15;
        int k0 = kb * 128;
        #pragma unroll
        for (int i = 0; i < 4; ++i) {
            int lin = (i * 256 + tid) * 8;
            int r = lin >> 6, d = lin & 63;
            const float* gp = &V[((size_t)(b * SL + k0 + r)) * EMB + h * HD + d];
            float4 f0 = *(const float4*)gp, f1 = *(const float4*)(gp + 4);
            uint2 u0 = { pk2(f0.x,f0.y), pk2(f0.z,f0.w) };
            uint2 u1 = { pk2(f1.x,f1.y), pk2(f1.z,f1.w) };
            *(uint2*)&sT[r * 68 + d]     = u0;
            *(uint2*)&sT[r * 68 + d + 4] = u1;
        }
        __syncthreads();
        #pragma unroll
        for (int p = 0; p < 4; ++p) {
            int d = p * 16 + (tid >> 4);
            int c = tid & 15;
            unsigned v[4];
            #pragma unroll
            for (int j = 0; j < 4; ++j) {
                unsigned lo = sT[(c * 8 + 2 * j) * 68 + d];
                unsigned hi = sT[(c * 8 + 2 * j + 1) * 68 + d];
                v[j] = lo | (hi << 16);
            }
            uint4 u = { v[0], v[1], v[2], v[3] };
            *(uint4*)&Vt[((size_t)(bh * HD + d)) * SL + k0 + c * 8] = u;
        }
    } else {
        int t = bid - 3072;
        int lane = tid & 63;
        #pragma unroll
        for (int r = 0; r < 4; ++r) {
            int wid = (t * 4 + (tid >> 6)) * 4 + r;
            int c = wid & 15, q = (wid >> 4) & 1023, bb = wid >> 14;
            int mv = mask[((size_t)bb * SL + q) * SL + c * 64 + lane];
            unsigned long long bits = __ballot(mv != 0);
            if (lane == 0) Mbt[((size_t)bb * 16 + c) * SL + q] = bits;
        }
    }
}

// ---------------- Flash attention v11: k-parity split, 32q/wave, 16 waves/CU ----------------
// 512 threads (8 waves), QB=128. Waves 0-3 process EVEN k-tiles, waves 4-7 ODD
// k-tiles; each wave owns 32 q-rows (wq=w&3), so K/V fragments are reused
// across 2 q-strips -> per-CU LDS read traffic halves vs v10 (the measured
// bottleneck pipe). O/l are additive across tiles -> one conflict-free LDS
// merge (34KB, planes of f32x4) + 2 barriers at the end. LDS = 4 tile-buffers
// (64KB): pair {2i,2i+1} computed while pair {2i+2,2i+3} stages; vmcnt(0) +
// one barrier per pair-iteration (loads span a full 2-tile compute). P stays
// in-register (permlane swaps); P-pack via v_cvt_pk_bf16_f32; mask via
// sign-shift+bfi; CSC pre-folded into Kb. XCD map: 8 bh per XCD.
__global__ __launch_bounds__(512, 4) void attn_mfma(
    const float* __restrict__ Q, const unsigned short* __restrict__ Kb,
    const unsigned short* __restrict__ Vt,
    const unsigned long long* __restrict__ Mbt,
    unsigned short* __restrict__ Oa)
{
    const int lin = blockIdx.x;
    const int xcd = lin & 7, slot = lin >> 3;
    const int bh = xcd * 8 + (slot >> 3);       // 8 bh per XCD
    const int q0 = (slot & 7) * QB;             // 8 q-tiles of that bh
    const int b = bh >> 4, h = bh & 15;
    const int tid = threadIdx.x;
    const int w = tid >> 6, lane = tid & 63;
    const int m16 = lane & 15, quad = lane >> 4;
    const int lr = lane >> 3, lc = lane & 7;
    const int grp = w >> 2;                     // 0: even tiles, 1: odd tiles
    const int wq = w & 3;                       // q-strip (32 rows each)
    const int srow = w * 8;                     // block-wide staging rows

    __shared__ __align__(16) unsigned short sAll[32768];    // 64 KB
    unsigned short* sKb = sAll;                 // 4 x 4096 shorts (K bufs)
    unsigned short* sVb = sAll + 16384;         // 4 x 4096 shorts (V bufs)

    const size_t vbase = (size_t)(bh * HD) * SL;   // Vt row d, len SL
    const size_t kbase = (size_t)(bh * SL) * HD;   // Kb row k, len 64
    const unsigned long long* Mp = Mbt + (size_t)(b * 16) * SL + q0 + wq * 32 + m16;

    // --- prologue: Q loads first (oldest vmem), then stage tiles 0,1 + masks ---
    float4 qf[2][4];
    #pragma unroll
    for (int u = 0; u < 2; ++u) {
        const float* qp = &Q[((size_t)(b * SL + q0 + wq * 32 + u * 16 + m16)) * EMB + h * HD + quad * 8];
        qf[u][0] = *(const float4*)qp;        qf[u][1] = *(const float4*)(qp + 4);
        qf[u][2] = *(const float4*)(qp + 32); qf[u][3] = *(const float4*)(qp + 36);
    }
    MEMPIN();
    #pragma unroll
    for (int t2 = 0; t2 < 2; ++t2) {
        gload_lds16(&Vt[vbase + (size_t)(srow + lr) * SL + t2 * 64 + (lc ^ lr) * 8],
                    &sVb[t2 * 4096 + srow * 64]);
        gload_lds16(&Kb[kbase + (size_t)(t2 * 64 + srow + lr) * HD + (lc ^ lr) * 8],
                    &sKb[t2 * 4096 + srow * 64]);
    }
    MEMPIN();
    unsigned long long mbC0 = Mp[(size_t)grp * SL];
    unsigned long long mbC1 = Mp[(size_t)grp * SL + 16];
    unsigned long long mbN0 = 0, mbN1 = 0;
    MEMPIN();

    bf16x8 bQ[2][2];
    #pragma unroll
    for (int u = 0; u < 2; ++u) {
        u32x4 u0 = { pk2(qf[u][0].x,qf[u][0].y), pk2(qf[u][0].z,qf[u][0].w),
                     pk2(qf[u][1].x,qf[u][1].y), pk2(qf[u][1].z,qf[u][1].w) };
        u32x4 u1 = { pk2(qf[u][2].x,qf[u][2].y), pk2(qf[u][2].z,qf[u][2].w),
                     pk2(qf[u][3].x,qf[u][3].y), pk2(qf[u][3].z,qf[u][3].w) };
        bQ[u][0] = __builtin_bit_cast(bf16x8, u0);
        bQ[u][1] = __builtin_bit_cast(bf16x8, u1);
    }

    f32x4 O[2][4] = {};
    f32x4 lacc[2] = {};
    const short one_bf = (short)0x3F80;
    const bf16x8 ones = { one_bf, one_bf, one_bf, one_bf, one_bf, one_bf, one_bf, one_bf };

    for (int i = 0; i < 8; ++i) {
        VMW(0);                                  // my staged loads (issued iter i-1) done
        __builtin_amdgcn_s_barrier();            // everyone's done; buffers for pair i ready
        __builtin_amdgcn_sched_barrier(0);

        const int t = 2 * i + grp;               // this wave's tile
        if (i < 7) {
            const int tE = 2 * i + 2;
            const int bE = tE & 3, bO = (tE + 1) & 3;
            gload_lds16(&Vt[vbase + (size_t)(srow + lr) * SL + tE * 64 + (lc ^ lr) * 8],
                        &sVb[bE * 4096 + srow * 64]);
            gload_lds16(&Kb[kbase + (size_t)(tE * 64 + srow + lr) * HD + (lc ^ lr) * 8],
                        &sKb[bE * 4096 + srow * 64]);
            gload_lds16(&Vt[vbase + (size_t)(srow + lr) * SL + (tE + 1) * 64 + (lc ^ lr) * 8],
                        &sVb[bO * 4096 + srow * 64]);
            gload_lds16(&Kb[kbase + (size_t)((tE + 1) * 64 + srow + lr) * HD + (lc ^ lr) * 8],
                        &sKb[bO * 4096 + srow * 64]);
            MEMPIN();
            mbN0 = Mp[(size_t)(t + 2) * SL];
            mbN1 = Mp[(size_t)(t + 2) * SL + 16];
            MEMPIN();
        }

        const unsigned short* kc = &sKb[(t & 3) * 4096];
        const unsigned short* vc = &sVb[(t & 3) * 4096];

        // scores: S^T[64k][32q], K-frag loaded once, used for both q-strips
        f32x4 sc[2][4];
        __builtin_amdgcn_s_setprio(1);
        #pragma unroll
        for (int t4 = 0; t4 < 4; ++t4) {
            int krow = t4 * 16 + m16;
            bf16x8 a0 = *(const bf16x8*)&kc[krow * 64 + ((quad ^ (krow & 7)) * 8)];
            bf16x8 a1 = *(const bf16x8*)&kc[krow * 64 + (((4 + quad) ^ (krow & 7)) * 8)];
            f32x4 z = {0.f, 0.f, 0.f, 0.f};
            sc[0][t4] = __builtin_amdgcn_mfma_f32_16x16x32_bf16(a0, bQ[0][0], z,         0,0,0);
            sc[0][t4] = __builtin_amdgcn_mfma_f32_16x16x32_bf16(a1, bQ[0][1], sc[0][t4], 0,0,0);
            sc[1][t4] = __builtin_amdgcn_mfma_f32_16x16x32_bf16(a0, bQ[1][0], z,         0,0,0);
            sc[1][t4] = __builtin_amdgcn_mfma_f32_16x16x32_bf16(a1, bQ[1][1], sc[1][t4], 0,0,0);
        }
        __builtin_amdgcn_s_setprio(0);

        // exp2 (CSC pre-folded into K) + in-register redistribution + mask
        bf16x8 bP[2][2];
        #pragma unroll
        for (int u = 0; u < 2; ++u) {
            unsigned long long mb = u ? mbC1 : mbC0;
            unsigned s0 = ((unsigned)mb) >> (quad * 8);
            unsigned s1 = ((unsigned)(mb >> 32)) >> (quad * 8);
            unsigned wt[4][2];
            #pragma unroll
            for (int t4 = 0; t4 < 4; ++t4) {
                wt[t4][0] = cvtpk(exp2_fast(sc[u][t4][0]), exp2_fast(sc[u][t4][1]));
                wt[t4][1] = cvtpk(exp2_fast(sc[u][t4][2]), exp2_fast(sc[u][t4][3]));
            }
            unsigned g[2][4];
            #pragma unroll
            for (int hh = 0; hh < 2; ++hh)
                #pragma unroll
                for (int p = 0; p < 2; ++p) {
                    unsigned A = wt[2 * hh][p], B = wt[2 * hh + 1][p];
                    asm("v_permlane32_swap_b32 %0, %1" : "+v"(A), "+v"(B));
                    asm("v_permlane16_swap_b32 %0, %1" : "+v"(A), "+v"(B));
                    g[hh][p] = A; g[hh][2 + p] = B;
                }
            #pragma unroll
            for (int hh = 0; hh < 2; ++hh) {
                unsigned sb = hh ? s1 : s0;
                #pragma unroll
                for (int j2 = 0; j2 < 4; ++j2) {
                    // full-word sign masks from bits (2j2, 2j2+1) -> bfe_i32; merge -> bfi
                    unsigned mlo = (unsigned)(((int)(sb << (31 - 2 * j2))) >> 31);
                    unsigned mhi = (unsigned)(((int)(sb << (30 - 2 * j2))) >> 31);
                    g[hh][j2] &= (mlo & 0xFFFFu) | (mhi & 0xFFFF0000u);
                }
            }
            u32x4 p0 = { g[0][0], g[0][1], g[0][2], g[0][3] };
            u32x4 p1 = { g[1][0], g[1][1], g[1][2], g[1][3] };
            bP[u][0] = __builtin_bit_cast(bf16x8, p0);
            bP[u][1] = __builtin_bit_cast(bf16x8, p1);
        }

        __builtin_amdgcn_s_setprio(1);
        // l partial: lacc += 1^T P
        lacc[0] = __builtin_amdgcn_mfma_f32_16x16x32_bf16(ones, bP[0][0], lacc[0], 0,0,0);
        lacc[0] = __builtin_amdgcn_mfma_f32_16x16x32_bf16(ones, bP[0][1], lacc[0], 0,0,0);
        lacc[1] = __builtin_amdgcn_mfma_f32_16x16x32_bf16(ones, bP[1][0], lacc[1], 0,0,0);
        lacc[1] = __builtin_amdgcn_mfma_f32_16x16x32_bf16(ones, bP[1][1], lacc[1], 0,0,0);

        // PV partial: O^T[64d][32q] += V^T P, V-frag reused across q-strips
        #pragma unroll
        for (int dt = 0; dt < 4; ++dt) {
            int drow = dt * 16 + m16;
            bf16x8 v0 = *(const bf16x8*)&vc[drow * 64 + ((quad ^ (drow & 7)) * 8)];
            bf16x8 v1 = *(const bf16x8*)&vc[drow * 64 + (((4 + quad) ^ (drow & 7)) * 8)];
            O[0][dt] = __builtin_amdgcn_mfma_f32_16x16x32_bf16(v0, bP[0][0], O[0][dt], 0,0,0);
            O[0][dt] = __builtin_amdgcn_mfma_f32_16x16x32_bf16(v1, bP[0][1], O[0][dt], 0,0,0);
            O[1][dt] = __builtin_amdgcn_mfma_f32_16x16x32_bf16(v0, bP[1][0], O[1][dt], 0,0,0);
            O[1][dt] = __builtin_amdgcn_mfma_f32_16x16x32_bf16(v1, bP[1][1], O[1][dt], 0,0,0);
        }
        __builtin_amdgcn_s_setprio(0);

        mbC0 = mbN0; mbC1 = mbN1;
    }

    // --- merge the two k-parity partials (group B -> LDS, group A adds) ---
    __syncthreads();
    float* sM = (float*)sAll;   // planes: 8 x [256 lanes x f32x4] + l: 256 x 2 f32 = 34 KB
    if (grp == 1) {
        #pragma unroll
        for (int u = 0; u < 2; ++u)
            #pragma unroll
            for (int dt = 0; dt < 4; ++dt)
                *(f32x4*)&sM[((u * 4 + dt) * 256 + wq * 64 + lane) * 4] = O[u][dt];
        sM[8192 + (wq * 64 + lane) * 2 + 0] = lacc[0][0];
        sM[8192 + (wq * 64 + lane) * 2 + 1] = lacc[1][0];
    }
    __syncthreads();
    if (grp == 0) {
        float l[2];
        l[0] = lacc[0][0] + sM[8192 + (wq * 64 + lane) * 2 + 0];
        l[1] = lacc[1][0] + sM[8192 + (wq * 64 + lane) * 2 + 1];
        #pragma unroll
        for (int u = 0; u < 2; ++u) {
            float inv = 1.f / l[u];
            size_t base = ((size_t)(b * SL + q0 + wq * 32 + u * 16 + m16)) * EMB + h * HD + quad * 4;
            #pragma unroll
            for (int dt = 0; dt < 4; ++dt) {
                f32x4 part = *(const f32x4*)&sM[((u * 4 + dt) * 256 + wq * 64 + lane) * 4];
                f32x4 o = O[u][dt] + part;
                uint2 ow = { cvtpk(o[0] * inv, o[1] * inv),
                             cvtpk(o[2] * inv, o[3] * inv) };
                *(uint2*)&Oa[base + dt * 16] = ow;
            }
        }
    }
}

// ---------------- Projection: C[4096][1024] = A_bf16 @ W_bf16^T + bias ----------------
__global__ __launch_bounds__(512, 2) void proj_mfma(
    const unsigned short* __restrict__ A, const unsigned short* __restrict__ Wb,
    const float* __restrict__ bias, float* __restrict__ C)
{
    const int n0 = blockIdx.x * 128;
    const int m0 = blockIdx.y * 128;
    const int tid = threadIdx.x;
    const int w = tid >> 6, lane = tid & 63;
    const int m16 = lane & 15, quad = lane >> 4;
    const int lr = lane >> 3, lc = lane & 7;
    const int wm = (w >> 2) * 64, wn = (w & 3) * 32;

    __shared__ __align__(16) unsigned short sA[2][128 * 64];
    __shared__ __align__(16) unsigned short sW[2][128 * 64];

    f32x4 acc[4][2] = {};

    #pragma unroll
    for (int i = 0; i < 2; ++i) {
        int r = w * 16 + i * 8;
        gload_lds16(&A [(size_t)(m0 + r + lr) * EMB + (lc ^ lr) * 8], &sA[0][r * 64]);
        gload_lds16(&Wb[(size_t)(n0 + r + lr) * EMB + (lc ^ lr) * 8], &sW[0][r * 64]);
    }
    __syncthreads();

    for (int it = 0; it < 16; ++it) {
        const int bf = it & 1;
        if (it < 15) {
            int e0 = (it + 1) * 64;
            #pragma unroll
            for (int i = 0; i < 2; ++i) {
                int r = w * 16 + i * 8;
                gload_lds16(&A [(size_t)(m0 + r + lr) * EMB + e0 + (lc ^ lr) * 8], &sA[bf ^ 1][r * 64]);
                gload_lds16(&Wb[(size_t)(n0 + r + lr) * EMB + e0 + (lc ^ lr) * 8], &sW[bf ^ 1][r * 64]);
            }
        }
        #pragma unroll
        for (int hh = 0; hh < 2; ++hh) {
            bf16x8 af[4], bw[2];
            #pragma unroll
            for (int mt = 0; mt < 4; ++mt) {
                int r = wm + mt * 16 + m16;
                af[mt] = *(const bf16x8*)&sA[bf][r * 64 + (((hh * 4 + quad) ^ (r & 7)) * 8)];
            }
            #pragma unroll
            for (int nt = 0; nt < 2; ++nt) {
                int r = wn + nt * 16 + m16;
                bw[nt] = *(const bf16x8*)&sW[bf][r * 64 + (((hh * 4 + quad) ^ (r & 7)) * 8)];
            }
            #pragma unroll
            for (int mt = 0; mt < 4; ++mt)
                #pragma unroll
                for (int nt = 0; nt < 2; ++nt)
                    acc[mt][nt] = __builtin_amdgcn_mfma_f32_16x16x32_bf16(af[mt], bw[nt], acc[mt][nt], 0,0,0);
        }
        __syncthreads();
    }

    #pragma unroll
    for (int nt = 0; nt < 2; ++nt) {
        float bv = bias[n0 + wn + nt * 16 + m16];
        #pragma unroll
        for (int mt = 0; mt < 4; ++mt) {
            size_t row = (size_t)(m0 + wm + mt * 16 + quad * 4);
            #pragma unroll
            for (int rg = 0; rg < 4; ++rg)
                C[(row + rg) * EMB + n0 + wn + nt * 16 + m16] = acc[mt][nt][rg] + bv;
        }
    }
}

extern "C" void kernel_launch(void* const* d_in, const int* in_sizes, int n_in,
                              void* d_out, int out_size, void* d_ws, size_t ws_size,
                              hipStream_t stream) {
    const float* Q    = (const float*)d_in[0];
    const float* K    = (const float*)d_in[1];
    const float* V    = (const float*)d_in[2];
    const int*   mask = (const int*)  d_in[3];
    const float* W    = (const float*)d_in[4];
    const float* bias = (const float*)d_in[5];

    unsigned short* Oa = (unsigned short*)d_ws;                              // 8.39 MB
    unsigned short* Wb = Oa + (size_t)NB * SL * EMB;                         // 2.10 MB
    unsigned long long* Mbt = (unsigned long long*)(Wb + (size_t)EMB * EMB); // 0.52 MB
    unsigned short* Vt = (unsigned short*)(Mbt + (size_t)NB * 16 * SL);      // 8.39 MB
    unsigned short* Kb = Vt + (size_t)NB * NH * HD * SL;                     // 8.39 MB

    prep<<<7168, 256, 0, stream>>>(W, Wb, K, Kb, V, Vt, mask, Mbt);
    attn_mfma<<<512, 512, 0, stream>>>(Q, Kb, Vt, Mbt, Oa);
    proj_mfma<<<dim3(EMB / 128, (NB * SL) / 128), 512, 0, stream>>>(Oa, Wb, bias, (float*)d_out);
}

// Round 7
// 155.152 us; speedup vs baseline: 1.6349x; 1.0311x over previous
//
#include <hip/hip_runtime.h>
#include <math.h>

#define NB 4
#define SL 1024
#define EMB 1024
#define NH 16
#define HD 64
#define QB 128

typedef __attribute__((ext_vector_type(8))) short bf16x8;
typedef __attribute__((ext_vector_type(4))) float f32x4;
typedef __attribute__((ext_vector_type(4))) unsigned u32x4;

// round-half-up f32->bf16 pack (inputs finite)
static __device__ __forceinline__ unsigned pk2(float a, float b) {
    unsigned x = __float_as_uint(a) + 0x8000u;
    unsigned y = __float_as_uint(b) + 0x8000u;
    return (x >> 16) | (y & 0xFFFF0000u);
}
static __device__ __forceinline__ float exp2_fast(float x) {
    float r; asm("v_exp_f32 %0, %1" : "=v"(r) : "v"(x)); return r;
}
// 2x f32 -> packed bf16 (RNE), single instruction
static __device__ __forceinline__ unsigned cvtpk(float a, float b) {
    unsigned r; asm("v_cvt_pk_bf16_f32 %0, %1, %2" : "=v"(r) : "v"(a), "v"(b)); return r;
}
static __device__ __forceinline__ void gload_lds16(const void* g, void* l) {
    __builtin_amdgcn_global_load_lds(
        (const __attribute__((address_space(1))) unsigned int*)g,
        (__attribute__((address_space(3))) unsigned int*)l, 16, 0, 0);
}

#define VMW(n) asm volatile("s_waitcnt vmcnt(" #n ")" ::: "memory")
#define MEMPIN() asm volatile("" ::: "memory")

// ---------------- Fused prep: W conv | K conv+split (xCSC) | V transpose | mask bitmask ----------------
__global__ __launch_bounds__(256) void prep(
    const float* __restrict__ W, unsigned short* __restrict__ Wb,
    const float* __restrict__ Kf, unsigned short* __restrict__ Kb,
    const float* __restrict__ V, unsigned short* __restrict__ Vt,
    const int* __restrict__ mask, unsigned long long* __restrict__ Mbt)
{
    __shared__ unsigned short sT[128 * 68];
    const int bid = blockIdx.x, tid = threadIdx.x;
    const float CSC = 0.125f * 1.44269504f;   // folded into K so scores are exp2-ready

    if (bid < 512) {
        int i = (bid * 256 + tid) * 8;
        float4 f0 = *(const float4*)&W[i];
        float4 f1 = *(const float4*)&W[i + 4];
        uint4 u = { pk2(f0.x,f0.y), pk2(f0.z,f0.w), pk2(f1.x,f1.y), pk2(f1.z,f1.w) };
        *(uint4*)&Wb[i] = u;
    } else if (bid < 2560) {
        int t = bid - 512;
        int b = t >> 9, h = (t >> 5) & 15, k0 = (t & 31) * 32;
        int r = tid >> 3, d = (tid & 7) * 8;
        const float* gp = &Kf[((size_t)(b * SL + k0 + r)) * EMB + h * HD + d];
        float4 f0 = *(const float4*)gp, f1 = *(const float4*)(gp + 4);
        uint4 u = { pk2(f0.x*CSC,f0.y*CSC), pk2(f0.z*CSC,f0.w*CSC),
                    pk2(f1.x*CSC,f1.y*CSC), pk2(f1.z*CSC,f1.w*CSC) };
        *(uint4*)&Kb[((size_t)((b * NH + h) * SL + k0 + r)) * HD + d] = u;
    } else if (bid < 3072) {
        int t = bid - 2560;
        int bh = t >> 3, kb = t & 7;
        int b = bh >> 4, h = bh & 15;
        int k0 = kb * 128;
        #pragma unroll
        for (int i = 0; i < 4; ++i) {
            int lin = (i * 256 + tid) * 8;
            int r = lin >> 6, d = lin & 63;
            const float* gp = &V[((size_t)(b * SL + k0 + r)) * EMB + h * HD + d];
            float4 f0 = *(const float4*)gp, f1 = *(const float4*)(gp + 4);
            uint2 u0 = { pk2(f0.x,f0.y), pk2(f0.z,f0.w) };
            uint2 u1 = { pk2(f1.x,f1.y), pk2(f1.z,f1.w) };
            *(uint2*)&sT[r * 68 + d]     = u0;
            *(uint2*)&sT[r * 68 + d + 4] = u1;
        }
        __syncthreads();
        #pragma unroll
        for (int p = 0; p < 4; ++p) {
            int d = p * 16 + (tid >> 4);
            int c = tid & 15;
            unsigned v[4];
            #pragma unroll
            for (int j = 0; j < 4; ++j) {
                unsigned lo = sT[(c * 8 + 2 * j) * 68 + d];
                unsigned hi = sT[(c * 8 + 2 * j + 1) * 68 + d];
                v[j] = lo | (hi << 16);
            }
            uint4 u = { v[0], v[1], v[2], v[3] };
            *(uint4*)&Vt[((size_t)(bh * HD + d)) * SL + k0 + c * 8] = u;
        }
    } else {
        int t = bid - 3072;
        int lane = tid & 63;
        #pragma unroll
        for (int r = 0; r < 4; ++r) {
            int wid = (t * 4 + (tid >> 6)) * 4 + r;
            int c = wid & 15, q = (wid >> 4) & 1023, bb = wid >> 14;
            int mv = mask[((size_t)bb * SL + q) * SL + c * 64 + lane];
            unsigned long long bits = __ballot(mv != 0);
            if (lane == 0) Mbt[((size_t)bb * 16 + c) * SL + q] = bits;
        }
    }
}

// ---------------- Flash attention v11: k-parity split, 32q/wave, 16 waves/CU ----------------
// (unchanged from R6 — best-known attn)
__global__ __launch_bounds__(512, 4) void attn_mfma(
    const float* __restrict__ Q, const unsigned short* __restrict__ Kb,
    const unsigned short* __restrict__ Vt,
    const unsigned long long* __restrict__ Mbt,
    unsigned short* __restrict__ Oa)
{
    const int lin = blockIdx.x;
    const int xcd = lin & 7, slot = lin >> 3;
    const int bh = xcd * 8 + (slot >> 3);       // 8 bh per XCD
    const int q0 = (slot & 7) * QB;             // 8 q-tiles of that bh
    const int b = bh >> 4, h = bh & 15;
    const int tid = threadIdx.x;
    const int w = tid >> 6, lane = tid & 63;
    const int m16 = lane & 15, quad = lane >> 4;
    const int lr = lane >> 3, lc = lane & 7;
    const int grp = w >> 2;                     // 0: even tiles, 1: odd tiles
    const int wq = w & 3;                       // q-strip (32 rows each)
    const int srow = w * 8;                     // block-wide staging rows

    __shared__ __align__(16) unsigned short sAll[32768];    // 64 KB
    unsigned short* sKb = sAll;                 // 4 x 4096 shorts (K bufs)
    unsigned short* sVb = sAll + 16384;         // 4 x 4096 shorts (V bufs)

    const size_t vbase = (size_t)(bh * HD) * SL;   // Vt row d, len SL
    const size_t kbase = (size_t)(bh * SL) * HD;   // Kb row k, len 64
    const unsigned long long* Mp = Mbt + (size_t)(b * 16) * SL + q0 + wq * 32 + m16;

    // --- prologue: Q loads first (oldest vmem), then stage tiles 0,1 + masks ---
    float4 qf[2][4];
    #pragma unroll
    for (int u = 0; u < 2; ++u) {
        const float* qp = &Q[((size_t)(b * SL + q0 + wq * 32 + u * 16 + m16)) * EMB + h * HD + quad * 8];
        qf[u][0] = *(const float4*)qp;        qf[u][1] = *(const float4*)(qp + 4);
        qf[u][2] = *(const float4*)(qp + 32); qf[u][3] = *(const float4*)(qp + 36);
    }
    MEMPIN();
    #pragma unroll
    for (int t2 = 0; t2 < 2; ++t2) {
        gload_lds16(&Vt[vbase + (size_t)(srow + lr) * SL + t2 * 64 + (lc ^ lr) * 8],
                    &sVb[t2 * 4096 + srow * 64]);
        gload_lds16(&Kb[kbase + (size_t)(t2 * 64 + srow + lr) * HD + (lc ^ lr) * 8],
                    &sKb[t2 * 4096 + srow * 64]);
    }
    MEMPIN();
    unsigned long long mbC0 = Mp[(size_t)grp * SL];
    unsigned long long mbC1 = Mp[(size_t)grp * SL + 16];
    unsigned long long mbN0 = 0, mbN1 = 0;
    MEMPIN();

    bf16x8 bQ[2][2];
    #pragma unroll
    for (int u = 0; u < 2; ++u) {
        u32x4 u0 = { pk2(qf[u][0].x,qf[u][0].y), pk2(qf[u][0].z,qf[u][0].w),
                     pk2(qf[u][1].x,qf[u][1].y), pk2(qf[u][1].z,qf[u][1].w) };
        u32x4 u1 = { pk2(qf[u][2].x,qf[u][2].y), pk2(qf[u][2].z,qf[u][2].w),
                     pk2(qf[u][3].x,qf[u][3].y), pk2(qf[u][3].z,qf[u][3].w) };
        bQ[u][0] = __builtin_bit_cast(bf16x8, u0);
        bQ[u][1] = __builtin_bit_cast(bf16x8, u1);
    }

    f32x4 O[2][4] = {};
    f32x4 lacc[2] = {};
    const short one_bf = (short)0x3F80;
    const bf16x8 ones = { one_bf, one_bf, one_bf, one_bf, one_bf, one_bf, one_bf, one_bf };

    for (int i = 0; i < 8; ++i) {
        VMW(0);                                  // my staged loads (issued iter i-1) done
        __builtin_amdgcn_s_barrier();            // everyone's done; buffers for pair i ready
        __builtin_amdgcn_sched_barrier(0);

        const int t = 2 * i + grp;               // this wave's tile
        if (i < 7) {
            const int tE = 2 * i + 2;
            const int bE = tE & 3, bO = (tE + 1) & 3;
            gload_lds16(&Vt[vbase + (size_t)(srow + lr) * SL + tE * 64 + (lc ^ lr) * 8],
                        &sVb[bE * 4096 + srow * 64]);
            gload_lds16(&Kb[kbase + (size_t)(tE * 64 + srow + lr) * HD + (lc ^ lr) * 8],
                        &sKb[bE * 4096 + srow * 64]);
            gload_lds16(&Vt[vbase + (size_t)(srow + lr) * SL + (tE + 1) * 64 + (lc ^ lr) * 8],
                        &sVb[bO * 4096 + srow * 64]);
            gload_lds16(&Kb[kbase + (size_t)((tE + 1) * 64 + srow + lr) * HD + (lc ^ lr) * 8],
                        &sKb[bO * 4096 + srow * 64]);
            MEMPIN();
            mbN0 = Mp[(size_t)(t + 2) * SL];
            mbN1 = Mp[(size_t)(t + 2) * SL + 16];
            MEMPIN();
        }

        const unsigned short* kc = &sKb[(t & 3) * 4096];
        const unsigned short* vc = &sVb[(t & 3) * 4096];

        // scores: S^T[64k][32q], K-frag loaded once, used for both q-strips
        f32x4 sc[2][4];
        __builtin_amdgcn_s_setprio(1);
        #pragma unroll
        for (int t4 = 0; t4 < 4; ++t4) {
            int krow = t4 * 16 + m16;
            bf16x8 a0 = *(const bf16x8*)&kc[krow * 64 + ((quad ^ (krow & 7)) * 8)];
            bf16x8 a1 = *(const bf16x8*)&kc[krow * 64 + (((4 + quad) ^ (krow & 7)) * 8)];
            f32x4 z = {0.f, 0.f, 0.f, 0.f};
            sc[0][t4] = __builtin_amdgcn_mfma_f32_16x16x32_bf16(a0, bQ[0][0], z,         0,0,0);
            sc[0][t4] = __builtin_amdgcn_mfma_f32_16x16x32_bf16(a1, bQ[0][1], sc[0][t4], 0,0,0);
            sc[1][t4] = __builtin_amdgcn_mfma_f32_16x16x32_bf16(a0, bQ[1][0], z,         0,0,0);
            sc[1][t4] = __builtin_amdgcn_mfma_f32_16x16x32_bf16(a1, bQ[1][1], sc[1][t4], 0,0,0);
        }
        __builtin_amdgcn_s_setprio(0);

        // exp2 (CSC pre-folded into K) + in-register redistribution + mask
        bf16x8 bP[2][2];
        #pragma unroll
        for (int u = 0; u < 2; ++u) {
            unsigned long long mb = u ? mbC1 : mbC0;
            unsigned s0 = ((unsigned)mb) >> (quad * 8);
            unsigned s1 = ((unsigned)(mb >> 32)) >> (quad * 8);
            unsigned wt[4][2];
            #pragma unroll
            for (int t4 = 0; t4 < 4; ++t4) {
                wt[t4][0] = cvtpk(exp2_fast(sc[u][t4][0]), exp2_fast(sc[u][t4][1]));
                wt[t4][1] = cvtpk(exp2_fast(sc[u][t4][2]), exp2_fast(sc[u][t4][3]));
            }
            unsigned g[2][4];
            #pragma unroll
            for (int hh = 0; hh < 2; ++hh)
                #pragma unroll
                for (int p = 0; p < 2; ++p) {
                    unsigned A = wt[2 * hh][p], B = wt[2 * hh + 1][p];
                    asm("v_permlane32_swap_b32 %0, %1" : "+v"(A), "+v"(B));
                    asm("v_permlane16_swap_b32 %0, %1" : "+v"(A), "+v"(B));
                    g[hh][p] = A; g[hh][2 + p] = B;
                }
            #pragma unroll
            for (int hh = 0; hh < 2; ++hh) {
                unsigned sb = hh ? s1 : s0;
                #pragma unroll
                for (int j2 = 0; j2 < 4; ++j2) {
                    unsigned mlo = (unsigned)(((int)(sb << (31 - 2 * j2))) >> 31);
                    unsigned mhi = (unsigned)(((int)(sb << (30 - 2 * j2))) >> 31);
                    g[hh][j2] &= (mlo & 0xFFFFu) | (mhi & 0xFFFF0000u);
                }
            }
            u32x4 p0 = { g[0][0], g[0][1], g[0][2], g[0][3] };
            u32x4 p1 = { g[1][0], g[1][1], g[1][2], g[1][3] };
            bP[u][0] = __builtin_bit_cast(bf16x8, p0);
            bP[u][1] = __builtin_bit_cast(bf16x8, p1);
        }

        __builtin_amdgcn_s_setprio(1);
        // l partial: lacc += 1^T P
        lacc[0] = __builtin_amdgcn_mfma_f32_16x16x32_bf16(ones, bP[0][0], lacc[0], 0,0,0);
        lacc[0] = __builtin_amdgcn_mfma_f32_16x16x32_bf16(ones, bP[0][1], lacc[0], 0,0,0);
        lacc[1] = __builtin_amdgcn_mfma_f32_16x16x32_bf16(ones, bP[1][0], lacc[1], 0,0,0);
        lacc[1] = __builtin_amdgcn_mfma_f32_16x16x32_bf16(ones, bP[1][1], lacc[1], 0,0,0);

        // PV partial: O^T[64d][32q] += V^T P, V-frag reused across q-strips
        #pragma unroll
        for (int dt = 0; dt < 4; ++dt) {
            int drow = dt * 16 + m16;
            bf16x8 v0 = *(const bf16x8*)&vc[drow * 64 + ((quad ^ (drow & 7)) * 8)];
            bf16x8 v1 = *(const bf16x8*)&vc[drow * 64 + (((4 + quad) ^ (drow & 7)) * 8)];
            O[0][dt] = __builtin_amdgcn_mfma_f32_16x16x32_bf16(v0, bP[0][0], O[0][dt], 0,0,0);
            O[0][dt] = __builtin_amdgcn_mfma_f32_16x16x32_bf16(v1, bP[0][1], O[0][dt], 0,0,0);
            O[1][dt] = __builtin_amdgcn_mfma_f32_16x16x32_bf16(v0, bP[1][0], O[1][dt], 0,0,0);
            O[1][dt] = __builtin_amdgcn_mfma_f32_16x16x32_bf16(v1, bP[1][1], O[1][dt], 0,0,0);
        }
        __builtin_amdgcn_s_setprio(0);

        mbC0 = mbN0; mbC1 = mbN1;
    }

    // --- merge the two k-parity partials (group B -> LDS, group A adds) ---
    __syncthreads();
    float* sM = (float*)sAll;   // planes: 8 x [256 lanes x f32x4] + l: 256 x 2 f32 = 34 KB
    if (grp == 1) {
        #pragma unroll
        for (int u = 0; u < 2; ++u)
            #pragma unroll
            for (int dt = 0; dt < 4; ++dt)
                *(f32x4*)&sM[((u * 4 + dt) * 256 + wq * 64 + lane) * 4] = O[u][dt];
        sM[8192 + (wq * 64 + lane) * 2 + 0] = lacc[0][0];
        sM[8192 + (wq * 64 + lane) * 2 + 1] = lacc[1][0];
    }
    __syncthreads();
    if (grp == 0) {
        float l[2];
        l[0] = lacc[0][0] + sM[8192 + (wq * 64 + lane) * 2 + 0];
        l[1] = lacc[1][0] + sM[8192 + (wq * 64 + lane) * 2 + 1];
        #pragma unroll
        for (int u = 0; u < 2; ++u) {
            float inv = 1.f / l[u];
            size_t base = ((size_t)(b * SL + q0 + wq * 32 + u * 16 + m16)) * EMB + h * HD + quad * 4;
            #pragma unroll
            for (int dt = 0; dt < 4; ++dt) {
                f32x4 part = *(const f32x4*)&sM[((u * 4 + dt) * 256 + wq * 64 + lane) * 4];
                f32x4 o = O[u][dt] + part;
                uint2 ow = { cvtpk(o[0] * inv, o[1] * inv),
                             cvtpk(o[2] * inv, o[3] * inv) };
                *(uint2*)&Oa[base + dt * 16] = ow;
            }
        }
    }
}

// ---------------- Projection v2: C[4096][1024] = A_bf16 @ W_bf16^T + bias ----------------
// 128x64 tile, 256 threads (4 waves, 2x2 of 64x32), grid 512 blocks ->
// 2 blocks/CU avg with 3-resident capacity (LDS 48KB, launch_bounds(256,3)):
// the per-iteration vmcnt(0)+barrier drains now hide behind other resident
// blocks (old proj: grid 256 = 1 block/CU, every drain exposed). XCD swizzle:
// each XCD owns 4 m-tiles x all 16 n-tiles -> per-XCD L2 set = 1MB A + 2.1MB Wb.
__global__ __launch_bounds__(256, 3) void proj_mfma(
    const unsigned short* __restrict__ A, const unsigned short* __restrict__ Wb,
    const float* __restrict__ bias, float* __restrict__ C)
{
    const int lin = blockIdx.x;
    const int xcd = lin & 7, idx = lin >> 3;
    const int m0 = (xcd * 4 + (idx >> 4)) * 128;   // 32 m-tiles
    const int n0 = (idx & 15) * 64;                // 16 n-tiles
    const int tid = threadIdx.x;
    const int w = tid >> 6, lane = tid & 63;
    const int m16 = lane & 15, quad = lane >> 4;
    const int lr = lane >> 3, lc = lane & 7;
    const int wm = (w >> 1) * 64, wn = (w & 1) * 32;

    __shared__ __align__(16) unsigned short sA[2][128 * 64];
    __shared__ __align__(16) unsigned short sW[2][64 * 64];

    f32x4 acc[4][2] = {};

    #pragma unroll
    for (int i = 0; i < 4; ++i) {
        int r = w * 32 + i * 8;
        gload_lds16(&A[(size_t)(m0 + r + lr) * EMB + (lc ^ lr) * 8], &sA[0][r * 64]);
    }
    #pragma unroll
    for (int i = 0; i < 2; ++i) {
        int r = w * 16 + i * 8;
        gload_lds16(&Wb[(size_t)(n0 + r + lr) * EMB + (lc ^ lr) * 8], &sW[0][r * 64]);
    }
    __syncthreads();

    for (int it = 0; it < 16; ++it) {
        const int bf = it & 1;
        if (it < 15) {
            int e0 = (it + 1) * 64;
            #pragma unroll
            for (int i = 0; i < 4; ++i) {
                int r = w * 32 + i * 8;
                gload_lds16(&A[(size_t)(m0 + r + lr) * EMB + e0 + (lc ^ lr) * 8], &sA[bf ^ 1][r * 64]);
            }
            #pragma unroll
            for (int i = 0; i < 2; ++i) {
                int r = w * 16 + i * 8;
                gload_lds16(&Wb[(size_t)(n0 + r + lr) * EMB + e0 + (lc ^ lr) * 8], &sW[bf ^ 1][r * 64]);
            }
        }
        #pragma unroll
        for (int hh = 0; hh < 2; ++hh) {
            bf16x8 af[4], bw[2];
            #pragma unroll
            for (int mt = 0; mt < 4; ++mt) {
                int r = wm + mt * 16 + m16;
                af[mt] = *(const bf16x8*)&sA[bf][r * 64 + (((hh * 4 + quad) ^ (r & 7)) * 8)];
            }
            #pragma unroll
            for (int nt = 0; nt < 2; ++nt) {
                int r = wn + nt * 16 + m16;
                bw[nt] = *(const bf16x8*)&sW[bf][r * 64 + (((hh * 4 + quad) ^ (r & 7)) * 8)];
            }
            #pragma unroll
            for (int mt = 0; mt < 4; ++mt)
                #pragma unroll
                for (int nt = 0; nt < 2; ++nt)
                    acc[mt][nt] = __builtin_amdgcn_mfma_f32_16x16x32_bf16(af[mt], bw[nt], acc[mt][nt], 0,0,0);
        }
        __syncthreads();
    }

    #pragma unroll
    for (int nt = 0; nt < 2; ++nt) {
        float bv = bias[n0 + wn + nt * 16 + m16];
        #pragma unroll
        for (int mt = 0; mt < 4; ++mt) {
            size_t row = (size_t)(m0 + wm + mt * 16 + quad * 4);
            #pragma unroll
            for (int rg = 0; rg < 4; ++rg)
                C[(row + rg) * EMB + n0 + wn + nt * 16 + m16] = acc[mt][nt][rg] + bv;
        }
    }
}

extern "C" void kernel_launch(void* const* d_in, const int* in_sizes, int n_in,
                              void* d_out, int out_size, void* d_ws, size_t ws_size,
                              hipStream_t stream) {
    const float* Q    = (const float*)d_in[0];
    const float* K    = (const float*)d_in[1];
    const float* V    = (const float*)d_in[2];
    const int*   mask = (const int*)  d_in[3];
    const float* W    = (const float*)d_in[4];
    const float* bias = (const float*)d_in[5];

    unsigned short* Oa = (unsigned short*)d_ws;                              // 8.39 MB
    unsigned short* Wb = Oa + (size_t)NB * SL * EMB;                         // 2.10 MB
    unsigned long long* Mbt = (unsigned long long*)(Wb + (size_t)EMB * EMB); // 0.52 MB
    unsigned short* Vt = (unsigned short*)(Mbt + (size_t)NB * 16 * SL);      // 8.39 MB
    unsigned short* Kb = Vt + (size_t)NB * NH * HD * SL;                     // 8.39 MB

    prep<<<7168, 256, 0, stream>>>(W, Wb, K, Kb, V, Vt, mask, Mbt);
    attn_mfma<<<512, 512, 0, stream>>>(Q, Kb, Vt, Mbt, Oa);
    proj_mfma<<<512, 256, 0, stream>>>(Oa, Wb, bias, (float*)d_out);
}

// Round 8
// 152.350 us; speedup vs baseline: 1.6649x; 1.0184x over previous
//
#include <hip/hip_runtime.h>
#include <math.h>

#define NB 4
#define SL 1024
#define EMB 1024
#define NH 16
#define HD 64
#define QB 128

typedef __attribute__((ext_vector_type(8))) short bf16x8;
typedef __attribute__((ext_vector_type(4))) float f32x4;
typedef __attribute__((ext_vector_type(4))) unsigned u32x4;

// round-half-up f32->bf16 pack (inputs finite)
static __device__ __forceinline__ unsigned pk2(float a, float b) {
    unsigned x = __float_as_uint(a) + 0x8000u;
    unsigned y = __float_as_uint(b) + 0x8000u;
    return (x >> 16) | (y & 0xFFFF0000u);
}
static __device__ __forceinline__ float exp2_fast(float x) {
    float r; asm("v_exp_f32 %0, %1" : "=v"(r) : "v"(x)); return r;
}
// 2x f32 -> packed bf16 (RNE), single instruction
static __device__ __forceinline__ unsigned cvtpk(float a, float b) {
    unsigned r; asm("v_cvt_pk_bf16_f32 %0, %1, %2" : "=v"(r) : "v"(a), "v"(b)); return r;
}
static __device__ __forceinline__ void gload_lds16(const void* g, void* l) {
    __builtin_amdgcn_global_load_lds(
        (const __attribute__((address_space(1))) unsigned int*)g,
        (__attribute__((address_space(3))) unsigned int*)l, 16, 0, 0);
}

#define VMW(n) asm volatile("s_waitcnt vmcnt(" #n ")" ::: "memory")
#define MEMPIN() asm volatile("" ::: "memory")

// ---------------- Fused prep: W conv | K conv+split (xCSC) | V transpose | mask bitmask ----------------
__global__ __launch_bounds__(256) void prep(
    const float* __restrict__ W, unsigned short* __restrict__ Wb,
    const float* __restrict__ Kf, unsigned short* __restrict__ Kb,
    const float* __restrict__ V, unsigned short* __restrict__ Vt,
    const int* __restrict__ mask, unsigned long long* __restrict__ Mbt)
{
    __shared__ unsigned short sT[128 * 68];
    const int bid = blockIdx.x, tid = threadIdx.x;
    const float CSC = 0.125f * 1.44269504f;   // folded into K so scores are exp2-ready

    if (bid < 512) {
        int i = (bid * 256 + tid) * 8;
        float4 f0 = *(const float4*)&W[i];
        float4 f1 = *(const float4*)&W[i + 4];
        uint4 u = { pk2(f0.x,f0.y), pk2(f0.z,f0.w), pk2(f1.x,f1.y), pk2(f1.z,f1.w) };
        *(uint4*)&Wb[i] = u;
    } else if (bid < 2560) {
        int t = bid - 512;
        int b = t >> 9, h = (t >> 5) & 15, k0 = (t & 31) * 32;
        int r = tid >> 3, d = (tid & 7) * 8;
        const float* gp = &Kf[((size_t)(b * SL + k0 + r)) * EMB + h * HD + d];
        float4 f0 = *(const float4*)gp, f1 = *(const float4*)(gp + 4);
        uint4 u = { pk2(f0.x*CSC,f0.y*CSC), pk2(f0.z*CSC,f0.w*CSC),
                    pk2(f1.x*CSC,f1.y*CSC), pk2(f1.z*CSC,f1.w*CSC) };
        *(uint4*)&Kb[((size_t)((b * NH + h) * SL + k0 + r)) * HD + d] = u;
    } else if (bid < 3072) {
        int t = bid - 2560;
        int bh = t >> 3, kb = t & 7;
        int b = bh >> 4, h = bh & 15;
        int k0 = kb * 128;
        #pragma unroll
        for (int i = 0; i < 4; ++i) {
            int lin = (i * 256 + tid) * 8;
            int r = lin >> 6, d = lin & 63;
            const float* gp = &V[((size_t)(b * SL + k0 + r)) * EMB + h * HD + d];
            float4 f0 = *(const float4*)gp, f1 = *(const float4*)(gp + 4);
            uint2 u0 = { pk2(f0.x,f0.y), pk2(f0.z,f0.w) };
            uint2 u1 = { pk2(f1.x,f1.y), pk2(f1.z,f1.w) };
            *(uint2*)&sT[r * 68 + d]     = u0;
            *(uint2*)&sT[r * 68 + d + 4] = u1;
        }
        __syncthreads();
        #pragma unroll
        for (int p = 0; p < 4; ++p) {
            int d = p * 16 + (tid >> 4);
            int c = tid & 15;
            unsigned v[4];
            #pragma unroll
            for (int j = 0; j < 4; ++j) {
                unsigned lo = sT[(c * 8 + 2 * j) * 68 + d];
                unsigned hi = sT[(c * 8 + 2 * j + 1) * 68 + d];
                v[j] = lo | (hi << 16);
            }
            uint4 u = { v[0], v[1], v[2], v[3] };
            *(uint4*)&Vt[((size_t)(bh * HD + d)) * SL + k0 + c * 8] = u;
        }
    } else {
        int t = bid - 3072;
        int lane = tid & 63;
        #pragma unroll
        for (int r = 0; r < 4; ++r) {
            int wid = (t * 4 + (tid >> 6)) * 4 + r;
            int c = wid & 15, q = (wid >> 4) & 1023, bb = wid >> 14;
            int mv = mask[((size_t)bb * SL + q) * SL + c * 64 + lane];
            unsigned long long bits = __ballot(mv != 0);
            if (lane == 0) Mbt[((size_t)bb * 16 + c) * SL + q] = bits;
        }
    }
}

// ---------------- Flash attention v11b: k-parity split, 32q/wave, 16 waves/CU ----------------
// R6 structure; only change: counted VMW(2) at loop top (issue order per iter
// is [4 gloads][2 mask loads]; only the gloads must retire for LDS visibility,
// the mask loads stay in flight and the compiler waits before their use).
__global__ __launch_bounds__(512, 4) void attn_mfma(
    const float* __restrict__ Q, const unsigned short* __restrict__ Kb,
    const unsigned short* __restrict__ Vt,
    const unsigned long long* __restrict__ Mbt,
    unsigned short* __restrict__ Oa)
{
    const int lin = blockIdx.x;
    const int xcd = lin & 7, slot = lin >> 3;
    const int bh = xcd * 8 + (slot >> 3);       // 8 bh per XCD
    const int q0 = (slot & 7) * QB;             // 8 q-tiles of that bh
    const int b = bh >> 4, h = bh & 15;
    const int tid = threadIdx.x;
    const int w = tid >> 6, lane = tid & 63;
    const int m16 = lane & 15, quad = lane >> 4;
    const int lr = lane >> 3, lc = lane & 7;
    const int grp = w >> 2;                     // 0: even tiles, 1: odd tiles
    const int wq = w & 3;                       // q-strip (32 rows each)
    const int srow = w * 8;                     // block-wide staging rows

    __shared__ __align__(16) unsigned short sAll[32768];    // 64 KB
    unsigned short* sKb = sAll;                 // 4 x 4096 shorts (K bufs)
    unsigned short* sVb = sAll + 16384;         // 4 x 4096 shorts (V bufs)

    const size_t vbase = (size_t)(bh * HD) * SL;   // Vt row d, len SL
    const size_t kbase = (size_t)(bh * SL) * HD;   // Kb row k, len 64
    const unsigned long long* Mp = Mbt + (size_t)(b * 16) * SL + q0 + wq * 32 + m16;

    // --- prologue: Q loads first (oldest vmem), then stage tiles 0,1 + masks ---
    float4 qf[2][4];
    #pragma unroll
    for (int u = 0; u < 2; ++u) {
        const float* qp = &Q[((size_t)(b * SL + q0 + wq * 32 + u * 16 + m16)) * EMB + h * HD + quad * 8];
        qf[u][0] = *(const float4*)qp;        qf[u][1] = *(const float4*)(qp + 4);
        qf[u][2] = *(const float4*)(qp + 32); qf[u][3] = *(const float4*)(qp + 36);
    }
    MEMPIN();
    #pragma unroll
    for (int t2 = 0; t2 < 2; ++t2) {
        gload_lds16(&Vt[vbase + (size_t)(srow + lr) * SL + t2 * 64 + (lc ^ lr) * 8],
                    &sVb[t2 * 4096 + srow * 64]);
        gload_lds16(&Kb[kbase + (size_t)(t2 * 64 + srow + lr) * HD + (lc ^ lr) * 8],
                    &sKb[t2 * 4096 + srow * 64]);
    }
    MEMPIN();
    unsigned long long mbC0 = Mp[(size_t)grp * SL];
    unsigned long long mbC1 = Mp[(size_t)grp * SL + 16];
    unsigned long long mbN0 = 0, mbN1 = 0;
    MEMPIN();

    bf16x8 bQ[2][2];
    #pragma unroll
    for (int u = 0; u < 2; ++u) {
        u32x4 u0 = { pk2(qf[u][0].x,qf[u][0].y), pk2(qf[u][0].z,qf[u][0].w),
                     pk2(qf[u][1].x,qf[u][1].y), pk2(qf[u][1].z,qf[u][1].w) };
        u32x4 u1 = { pk2(qf[u][2].x,qf[u][2].y), pk2(qf[u][2].z,qf[u][2].w),
                     pk2(qf[u][3].x,qf[u][3].y), pk2(qf[u][3].z,qf[u][3].w) };
        bQ[u][0] = __builtin_bit_cast(bf16x8, u0);
        bQ[u][1] = __builtin_bit_cast(bf16x8, u1);
    }

    f32x4 O[2][4] = {};
    f32x4 lacc[2] = {};
    const short one_bf = (short)0x3F80;
    const bf16x8 ones = { one_bf, one_bf, one_bf, one_bf, one_bf, one_bf, one_bf, one_bf };

    for (int i = 0; i < 8; ++i) {
        VMW(2);                                  // my 4 gloads done; 2 mask loads stay in flight
        __builtin_amdgcn_s_barrier();            // everyone's gloads done; buffers for pair i ready
        __builtin_amdgcn_sched_barrier(0);

        const int t = 2 * i + grp;               // this wave's tile
        if (i < 7) {
            const int tE = 2 * i + 2;
            const int bE = tE & 3, bO = (tE + 1) & 3;
            gload_lds16(&Vt[vbase + (size_t)(srow + lr) * SL + tE * 64 + (lc ^ lr) * 8],
                        &sVb[bE * 4096 + srow * 64]);
            gload_lds16(&Kb[kbase + (size_t)(tE * 64 + srow + lr) * HD + (lc ^ lr) * 8],
                        &sKb[bE * 4096 + srow * 64]);
            gload_lds16(&Vt[vbase + (size_t)(srow + lr) * SL + (tE + 1) * 64 + (lc ^ lr) * 8],
                        &sVb[bO * 4096 + srow * 64]);
            gload_lds16(&Kb[kbase + (size_t)((tE + 1) * 64 + srow + lr) * HD + (lc ^ lr) * 8],
                        &sKb[bO * 4096 + srow * 64]);
            MEMPIN();   // keep mb loads AFTER the gloads (vmcnt arithmetic)
            mbN0 = Mp[(size_t)(t + 2) * SL];
            mbN1 = Mp[(size_t)(t + 2) * SL + 16];
            MEMPIN();
        }

        const unsigned short* kc = &sKb[(t & 3) * 4096];
        const unsigned short* vc = &sVb[(t & 3) * 4096];

        // scores: S^T[64k][32q], K-frag loaded once, used for both q-strips
        f32x4 sc[2][4];
        __builtin_amdgcn_s_setprio(1);
        #pragma unroll
        for (int t4 = 0; t4 < 4; ++t4) {
            int krow = t4 * 16 + m16;
            bf16x8 a0 = *(const bf16x8*)&kc[krow * 64 + ((quad ^ (krow & 7)) * 8)];
            bf16x8 a1 = *(const bf16x8*)&kc[krow * 64 + (((4 + quad) ^ (krow & 7)) * 8)];
            f32x4 z = {0.f, 0.f, 0.f, 0.f};
            sc[0][t4] = __builtin_amdgcn_mfma_f32_16x16x32_bf16(a0, bQ[0][0], z,         0,0,0);
            sc[0][t4] = __builtin_amdgcn_mfma_f32_16x16x32_bf16(a1, bQ[0][1], sc[0][t4], 0,0,0);
            sc[1][t4] = __builtin_amdgcn_mfma_f32_16x16x32_bf16(a0, bQ[1][0], z,         0,0,0);
            sc[1][t4] = __builtin_amdgcn_mfma_f32_16x16x32_bf16(a1, bQ[1][1], sc[1][t4], 0,0,0);
        }
        __builtin_amdgcn_s_setprio(0);

        // exp2 (CSC pre-folded into K) + in-register redistribution + mask
        bf16x8 bP[2][2];
        #pragma unroll
        for (int u = 0; u < 2; ++u) {
            unsigned long long mb = u ? mbC1 : mbC0;
            unsigned s0 = ((unsigned)mb) >> (quad * 8);
            unsigned s1 = ((unsigned)(mb >> 32)) >> (quad * 8);
            unsigned wt[4][2];
            #pragma unroll
            for (int t4 = 0; t4 < 4; ++t4) {
                wt[t4][0] = cvtpk(exp2_fast(sc[u][t4][0]), exp2_fast(sc[u][t4][1]));
                wt[t4][1] = cvtpk(exp2_fast(sc[u][t4][2]), exp2_fast(sc[u][t4][3]));
            }
            unsigned g[2][4];
            #pragma unroll
            for (int hh = 0; hh < 2; ++hh)
                #pragma unroll
                for (int p = 0; p < 2; ++p) {
                    unsigned A = wt[2 * hh][p], B = wt[2 * hh + 1][p];
                    asm("v_permlane32_swap_b32 %0, %1" : "+v"(A), "+v"(B));
                    asm("v_permlane16_swap_b32 %0, %1" : "+v"(A), "+v"(B));
                    g[hh][p] = A; g[hh][2 + p] = B;
                }
            #pragma unroll
            for (int hh = 0; hh < 2; ++hh) {
                unsigned sb = hh ? s1 : s0;
                #pragma unroll
                for (int j2 = 0; j2 < 4; ++j2) {
                    unsigned mlo = (unsigned)(((int)(sb << (31 - 2 * j2))) >> 31);
                    unsigned mhi = (unsigned)(((int)(sb << (30 - 2 * j2))) >> 31);
                    g[hh][j2] &= (mlo & 0xFFFFu) | (mhi & 0xFFFF0000u);
                }
            }
            u32x4 p0 = { g[0][0], g[0][1], g[0][2], g[0][3] };
            u32x4 p1 = { g[1][0], g[1][1], g[1][2], g[1][3] };
            bP[u][0] = __builtin_bit_cast(bf16x8, p0);
            bP[u][1] = __builtin_bit_cast(bf16x8, p1);
        }

        __builtin_amdgcn_s_setprio(1);
        // l partial: lacc += 1^T P
        lacc[0] = __builtin_amdgcn_mfma_f32_16x16x32_bf16(ones, bP[0][0], lacc[0], 0,0,0);
        lacc[0] = __builtin_amdgcn_mfma_f32_16x16x32_bf16(ones, bP[0][1], lacc[0], 0,0,0);
        lacc[1] = __builtin_amdgcn_mfma_f32_16x16x32_bf16(ones, bP[1][0], lacc[1], 0,0,0);
        lacc[1] = __builtin_amdgcn_mfma_f32_16x16x32_bf16(ones, bP[1][1], lacc[1], 0,0,0);

        // PV partial: O^T[64d][32q] += V^T P, V-frag reused across q-strips
        #pragma unroll
        for (int dt = 0; dt < 4; ++dt) {
            int drow = dt * 16 + m16;
            bf16x8 v0 = *(const bf16x8*)&vc[drow * 64 + ((quad ^ (drow & 7)) * 8)];
            bf16x8 v1 = *(const bf16x8*)&vc[drow * 64 + (((4 + quad) ^ (drow & 7)) * 8)];
            O[0][dt] = __builtin_amdgcn_mfma_f32_16x16x32_bf16(v0, bP[0][0], O[0][dt], 0,0,0);
            O[0][dt] = __builtin_amdgcn_mfma_f32_16x16x32_bf16(v1, bP[0][1], O[0][dt], 0,0,0);
            O[1][dt] = __builtin_amdgcn_mfma_f32_16x16x32_bf16(v0, bP[1][0], O[1][dt], 0,0,0);
            O[1][dt] = __builtin_amdgcn_mfma_f32_16x16x32_bf16(v1, bP[1][1], O[1][dt], 0,0,0);
        }
        __builtin_amdgcn_s_setprio(0);

        mbC0 = mbN0; mbC1 = mbN1;
    }

    // --- merge the two k-parity partials (group B -> LDS, group A adds) ---
    __syncthreads();
    float* sM = (float*)sAll;   // planes: 8 x [256 lanes x f32x4] + l: 256 x 2 f32 = 34 KB
    if (grp == 1) {
        #pragma unroll
        for (int u = 0; u < 2; ++u)
            #pragma unroll
            for (int dt = 0; dt < 4; ++dt)
                *(f32x4*)&sM[((u * 4 + dt) * 256 + wq * 64 + lane) * 4] = O[u][dt];
        sM[8192 + (wq * 64 + lane) * 2 + 0] = lacc[0][0];
        sM[8192 + (wq * 64 + lane) * 2 + 1] = lacc[1][0];
    }
    __syncthreads();
    if (grp == 0) {
        float l[2];
        l[0] = lacc[0][0] + sM[8192 + (wq * 64 + lane) * 2 + 0];
        l[1] = lacc[1][0] + sM[8192 + (wq * 64 + lane) * 2 + 1];
        #pragma unroll
        for (int u = 0; u < 2; ++u) {
            float inv = 1.f / l[u];
            size_t base = ((size_t)(b * SL + q0 + wq * 32 + u * 16 + m16)) * EMB + h * HD + quad * 4;
            #pragma unroll
            for (int dt = 0; dt < 4; ++dt) {
                f32x4 part = *(const f32x4*)&sM[((u * 4 + dt) * 256 + wq * 64 + lane) * 4];
                f32x4 o = O[u][dt] + part;
                uint2 ow = { cvtpk(o[0] * inv, o[1] * inv),
                             cvtpk(o[2] * inv, o[3] * inv) };
                *(uint2*)&Oa[base + dt * 16] = ow;
            }
        }
    }
}

// ---------------- Projection v3: C[4096][1024] = A_bf16 @ W_bf16^T + bias ----------------
// 128x64 tile, 256 threads, grid 512. Depth-2 counted-vmcnt pipeline (T3+T4):
// 3 LDS buffers (73.7KB -> 2 blocks/CU), raw s_barrier, VMW(6) keeps the next
// iter's 6 gloads in flight across the barrier (old: __syncthreads drained
// vmcnt(0) 16x with only 2 blocks/CU to hide it). Buffer (it+2)%3 = it-1's
// buffer, whose reads completed before this iter's barrier -> race-free.
__global__ __launch_bounds__(256, 2) void proj_mfma(
    const unsigned short* __restrict__ A, const unsigned short* __restrict__ Wb,
    const float* __restrict__ bias, float* __restrict__ C)
{
    const int lin = blockIdx.x;
    const int xcd = lin & 7, idx = lin >> 3;
    const int m0 = (xcd * 4 + (idx >> 4)) * 128;   // 32 m-tiles
    const int n0 = (idx & 15) * 64;                // 16 n-tiles
    const int tid = threadIdx.x;
    const int w = tid >> 6, lane = tid & 63;
    const int m16 = lane & 15, quad = lane >> 4;
    const int lr = lane >> 3, lc = lane & 7;
    const int wm = (w >> 1) * 64, wn = (w & 1) * 32;

    __shared__ __align__(16) unsigned short sA[3][128 * 64];
    __shared__ __align__(16) unsigned short sW[3][64 * 64];

    f32x4 acc[4][2] = {};

    // stage K-slice IT into buffer BI: per wave 4 A-gloads + 2 W-gloads (6 vmem)
    #define PSTAGE(IT, BI)                                                        \
    {                                                                             \
        const int e0_ = (IT) * 64;                                                \
        _Pragma("unroll")                                                         \
        for (int i_ = 0; i_ < 4; ++i_) {                                          \
            int r_ = w * 32 + i_ * 8;                                             \
            gload_lds16(&A[(size_t)(m0 + r_ + lr) * EMB + e0_ + (lc ^ lr) * 8],   \
                        &sA[BI][r_ * 64]);                                        \
        }                                                                         \
        _Pragma("unroll")                                                         \
        for (int i_ = 0; i_ < 2; ++i_) {                                          \
            int r_ = w * 16 + i_ * 8;                                             \
            gload_lds16(&Wb[(size_t)(n0 + r_ + lr) * EMB + e0_ + (lc ^ lr) * 8],  \
                        &sW[BI][r_ * 64]);                                        \
        }                                                                         \
    }

    PSTAGE(0, 0)
    MEMPIN();          // pin issue order: it0's 6 strictly older than it1's 6
    PSTAGE(1, 1)
    MEMPIN();

    for (int it = 0; it < 16; ++it) {
        if (it < 15) { VMW(6); } else { VMW(0); }   // my 6 for this iter retired
        __builtin_amdgcn_s_barrier();
        __builtin_amdgcn_sched_barrier(0);

        if (it < 14) {
            const int bn = (it + 2) % 3;
            PSTAGE(it + 2, bn)
            MEMPIN();
        }

        const int bf = it % 3;
        #pragma unroll
        for (int hh = 0; hh < 2; ++hh) {
            bf16x8 af[4], bw[2];
            #pragma unroll
            for (int mt = 0; mt < 4; ++mt) {
                int r = wm + mt * 16 + m16;
                af[mt] = *(const bf16x8*)&sA[bf][r * 64 + (((hh * 4 + quad) ^ (r & 7)) * 8)];
            }
            #pragma unroll
            for (int nt = 0; nt < 2; ++nt) {
                int r = wn + nt * 16 + m16;
                bw[nt] = *(const bf16x8*)&sW[bf][r * 64 + (((hh * 4 + quad) ^ (r & 7)) * 8)];
            }
            #pragma unroll
            for (int mt = 0; mt < 4; ++mt)
                #pragma unroll
                for (int nt = 0; nt < 2; ++nt)
                    acc[mt][nt] = __builtin_amdgcn_mfma_f32_16x16x32_bf16(af[mt], bw[nt], acc[mt][nt], 0,0,0);
        }
    }

    #pragma unroll
    for (int nt = 0; nt < 2; ++nt) {
        float bv = bias[n0 + wn + nt * 16 + m16];
        #pragma unroll
        for (int mt = 0; mt < 4; ++mt) {
            size_t row = (size_t)(m0 + wm + mt * 16 + quad * 4);
            #pragma unroll
            for (int rg = 0; rg < 4; ++rg)
                C[(row + rg) * EMB + n0 + wn + nt * 16 + m16] = acc[mt][nt][rg] + bv;
        }
    }
}

extern "C" void kernel_launch(void* const* d_in, const int* in_sizes, int n_in,
                              void* d_out, int out_size, void* d_ws, size_t ws_size,
                              hipStream_t stream) {
    const float* Q    = (const float*)d_in[0];
    const float* K    = (const float*)d_in[1];
    const float* V    = (const float*)d_in[2];
    const int*   mask = (const int*)  d_in[3];
    const float* W    = (const float*)d_in[4];
    const float* bias = (const float*)d_in[5];

    unsigned short* Oa = (unsigned short*)d_ws;                              // 8.39 MB
    unsigned short* Wb = Oa + (size_t)NB * SL * EMB;                         // 2.10 MB
    unsigned long long* Mbt = (unsigned long long*)(Wb + (size_t)EMB * EMB); // 0.52 MB
    unsigned short* Vt = (unsigned short*)(Mbt + (size_t)NB * 16 * SL);      // 8.39 MB
    unsigned short* Kb = Vt + (size_t)NB * NH * HD * SL;                     // 8.39 MB

    prep<<<7168, 256, 0, stream>>>(W, Wb, K, Kb, V, Vt, mask, Mbt);
    attn_mfma<<<512, 512, 0, stream>>>(Q, Kb, Vt, Mbt, Oa);
    proj_mfma<<<512, 256, 0, stream>>>(Oa, Wb, bias, (float*)d_out);
}